// Round 14
// baseline (654.649 us; speedup 1.0000x reference)
//
#include <hip/hip_runtime.h>

#define BN_EPS 1e-5f

// ---------------- embedding: h = x @ W_emb + b_emb  (x is [N,4]) ----------------
__global__ void k_embed(const float* __restrict__ x, const float* __restrict__ Wemb,
                        const float* __restrict__ bemb, float* __restrict__ h, int N) {
    int t = blockIdx.x * blockDim.x + threadIdx.x;
    int n = t >> 6, c = t & 63;
    if (n >= N) return;
    const float* xr = x + (size_t)n * 4;
    float acc = bemb[c];
    acc += xr[0] * Wemb[0 * 64 + c];
    acc += xr[1] * Wemb[1 * 64 + c];
    acc += xr[2] * Wemb[2 * 64 + c];
    acc += xr[3] * Wemb[3 * 64 + c];
    h[t] = acc;
}

// ---------------- CSR build: histogram of dst ----------------
__global__ void k_hist(const int* __restrict__ dst, int* __restrict__ deg, int E) {
    int e = blockIdx.x * blockDim.x + threadIdx.x;
    if (e < E) atomicAdd(&deg[dst[e]], 1);
}

// ---------------- scan phase 1: per-block sums (1024 elems / 256-thread block) --
__global__ __launch_bounds__(256) void k_blocksum(const int* __restrict__ deg,
                                                  int* __restrict__ bsum, int N) {
    __shared__ int red[256];
    int tid = threadIdx.x;
    int base = blockIdx.x * 1024 + tid * 4;
    int s = 0;
    if (base + 3 < N) {
        int4 v = *(const int4*)&deg[base];
        s = v.x + v.y + v.z + v.w;
    } else {
        for (int i = 0; i < 4; ++i) if (base + i < N) s += deg[base + i];
    }
    red[tid] = s;
    __syncthreads();
    for (int d = 128; d > 0; d >>= 1) {
        if (tid < d) red[tid] += red[tid + d];
        __syncthreads();
    }
    if (tid == 0) bsum[blockIdx.x] = red[0];
}

// ---------------- scan phase 2: exclusive scan of block sums (nb <= 1024) -------
__global__ __launch_bounds__(1024) void k_scanpartials(int* __restrict__ bsum, int nb) {
    __shared__ int t[1024];
    int tid = threadIdx.x;
    int v = (tid < nb) ? bsum[tid] : 0;
    t[tid] = v;
    __syncthreads();
    for (int d = 1; d < 1024; d <<= 1) {
        int u = (tid >= d) ? t[tid - d] : 0;
        __syncthreads();
        t[tid] += u;
        __syncthreads();
    }
    if (tid < nb) bsum[tid] = t[tid] - v;  // exclusive
}

// ---------------- scan phase 3: per-block exclusive scan + offset, write rowptr -
__global__ __launch_bounds__(256) void k_applyscan(const int* __restrict__ deg,
                                                   const int* __restrict__ bsum,
                                                   int* __restrict__ rowptr, int N, int E) {
    __shared__ int red[256];
    int tid = threadIdx.x;
    int base = blockIdx.x * 1024 + tid * 4;
    int v0 = 0, v1 = 0, v2 = 0, v3 = 0;
    if (base + 3 < N) {
        int4 v = *(const int4*)&deg[base];
        v0 = v.x; v1 = v.y; v2 = v.z; v3 = v.w;
    } else {
        if (base < N) v0 = deg[base];
        if (base + 1 < N) v1 = deg[base + 1];
        if (base + 2 < N) v2 = deg[base + 2];
        if (base + 3 < N) v3 = deg[base + 3];
    }
    int s = v0 + v1 + v2 + v3;
    red[tid] = s;
    __syncthreads();
    for (int d = 1; d < 256; d <<= 1) {
        int u = (tid >= d) ? red[tid - d] : 0;
        __syncthreads();
        red[tid] += u;
        __syncthreads();
    }
    int off = bsum[blockIdx.x] + red[tid] - s;
    int r0 = off, r1 = off + v0, r2 = r1 + v1, r3 = r2 + v2;
    if (base < N)     rowptr[base] = r0;
    if (base + 1 < N) rowptr[base + 1] = r1;
    if (base + 2 < N) rowptr[base + 2] = r2;
    if (base + 3 < N) rowptr[base + 3] = r3;
    if (blockIdx.x == 0 && tid == 0) rowptr[N] = E;
}

// ---------------- init per-bucket cursors: gcur[b] = rowptr[b*256] --------------
__global__ void k_initbcur(const int* __restrict__ rowptr, int* __restrict__ gcur,
                           int NB, int N) {
    int b = blockIdx.x * blockDim.x + threadIdx.x;
    if (b < NB) {
        int node = b << 8; if (node > N) node = N;
        gcur[b] = rowptr[node];
    }
}

// ------- sort pass A: partition edges into 256-node buckets (requires N < 2^24) -
#define ABLK 8192
__global__ __launch_bounds__(1024) void k_binA(const int* __restrict__ src,
                                               const int* __restrict__ dst,
                                               const float* __restrict__ attr,
                                               int* __restrict__ gcur,
                                               unsigned long long* __restrict__ tmp,
                                               int E, int N) {
    __shared__ int hist[1024];
    __shared__ int lcur[1024];
    int tid = threadIdx.x;
    int NB = (N + 255) >> 8;  // <= 1024 for N <= 262144
    int e0 = blockIdx.x * ABLK;
    int e1 = e0 + ABLK; if (e1 > E) e1 = E;
    for (int i = tid; i < NB; i += 1024) hist[i] = 0;
    __syncthreads();
    for (int e = e0 + tid; e < e1; e += 1024) atomicAdd(&hist[dst[e] >> 8], 1);
    __syncthreads();
    for (int b = tid; b < NB; b += 1024) {
        int hc = hist[b];
        lcur[b] = hc ? atomicAdd(&gcur[b], hc) : 0;
    }
    __syncthreads();
    for (int e = e0 + tid; e < e1; e += 1024) {
        int d = dst[e];
        int pos = atomicAdd(&lcur[d >> 8], 1);
        unsigned long long p = ((unsigned long long)__float_as_uint(attr[e]) << 32) |
                               ((unsigned long long)(d & 255) << 24) |
                               (unsigned int)src[e];
        tmp[pos] = p;
    }
}

// ------- sort pass B: one block per bucket; exact node placement via LDS cursors.
__global__ __launch_bounds__(256) void k_binB(const int* __restrict__ rowptr,
                                              const unsigned long long* __restrict__ tmp,
                                              unsigned long long* __restrict__ edata,
                                              int N) {
    __shared__ int cur[256];
    int b = blockIdx.x;
    int tid = threadIdx.x;
    int nb0 = b << 8;
    int node = nb0 + tid;
    cur[tid] = (node < N) ? rowptr[node] : 0;
    int beg = rowptr[nb0];
    int endnode = nb0 + 256; if (endnode > N) endnode = N;
    int end = rowptr[endnode];
    __syncthreads();
    for (int e = beg + tid; e < end; e += 256) {
        unsigned long long p = tmp[e];
        int dl = (int)((p >> 24) & 255);
        int pos = atomicAdd(&cur[dl], 1);
        edata[pos] = p & 0xFFFFFFFF00FFFFFFull;  // clear dstlow: [attr | src]
    }
}

// ---- inline BN scale/shift from raw stats (replaces the k_bnfinish kernel) ----
__device__ __forceinline__ void bn_coeff(const float* bs, const float* gam,
                                         const float* bet, int c, float inv_n,
                                         float& sc, float& sh) {
    float mean = bs[c] * inv_n;
    float var = bs[64 + c] * inv_n - mean * mean;
    sc = gam[c] * rsqrtf(fmaxf(var, 0.f) + BN_EPS);
    sh = bet[c] - mean * sc;
}

// ------- pull gather with lazy BN: S[n] = sum_e w_e * act(h_raw[src_e]) --------
__global__ void k_gather(const int* __restrict__ rowptr,
                         const unsigned long long* __restrict__ edata,
                         const float* __restrict__ h,
                         const float* __restrict__ bsp, const float* __restrict__ gamp,
                         const float* __restrict__ betp, int act,
                         float* __restrict__ S, float* __restrict__ degw, int N) {
    int t = blockIdx.x * blockDim.x + threadIdx.x;
    int n = t >> 6, c = t & 63;
    if (n >= N) return;
    float sc = 1.f, sh = 0.f;
    if (act) bn_coeff(bsp, gamp, betp, c, 1.f / (float)N, sc, sh);
    int beg = rowptr[n], end = rowptr[n + 1];
    int len = end - beg;
    float acc[8] = {0.f, 0.f, 0.f, 0.f, 0.f, 0.f, 0.f, 0.f};
    float wsum = 0.f;
    for (int base = 0; base < len; base += 8) {
#pragma unroll
        for (int i = 0; i < 8; ++i) {
            int idx = base + i;
            int ce = beg + (idx < len ? idx : len - 1);  // wave-uniform predicate
            unsigned long long p = edata[ce];
            float w = (idx < len) ? __uint_as_float((unsigned int)(p >> 32)) : 0.f;
            int s = (int)(unsigned int)p;
            float v = h[(size_t)s * 64 + c];
            if (act) v = fmaxf(fmaf(v, sc, sh), 0.f);
            acc[i] += w * v;
            wsum += w;
        }
    }
    float r = ((acc[0] + acc[1]) + (acc[2] + acc[3])) +
              ((acc[4] + acc[5]) + (acc[6] + acc[7]));
    S[(size_t)n * 64 + c] = r;
    if (c == 0) degw[n] = wsum;
}

// --- h_raw_out = S@W1 + x@W3 - dw*(x@W2) + dw*b1 + b3 (in place, x=act(h_raw));
// R10 structure + b128 LDS accesses: weights stored TRANSPOSED in LDS
// (WT[c][k], row stride 68 floats: 16B-aligned, conflict-free for b128) so
// each lane reads 4 k-values of its column with one ds_read_b128; row values
// read as wave-uniform float4 broadcasts. Per 4-k group: 11 b128 + 48 FMA
// (vs 44 b32 + 48 FMA before) -- removes the LDS-issue bottleneck.
// R11 (v_readlane) and R12 (s_load) both regressed -- do not revisit.
#define WPAD 68
__global__ __launch_bounds__(256) void k_update(
    const float* __restrict__ S, float* __restrict__ h,
    const float* __restrict__ degw,
    const float* __restrict__ bsp, const float* __restrict__ gamp,
    const float* __restrict__ betp, int act,
    const float* __restrict__ W1, const float* __restrict__ b1,
    const float* __restrict__ W2, const float* __restrict__ W3,
    const float* __restrict__ b3,
    float* __restrict__ bnstats, int N) {
    __shared__ float W1s[64 * WPAD], W2s[64 * WPAD], W3s[64 * WPAD];  // [c][k]
    __shared__ float sS[16 * 64], sh[16 * 64];
    __shared__ float dwS[16];
    int tid = threadIdx.x;
    // stage weights transposed: WT[c][k] = W[k][c] (once per block)
    for (int i = tid * 4; i < 4096; i += 1024) {
        int k = i >> 6, cc = i & 63;  // cc..cc+3 channels at row k
        float4 w1 = *(const float4*)&W1[i];
        float4 w2 = *(const float4*)&W2[i];
        float4 w3 = *(const float4*)&W3[i];
        W1s[(cc + 0) * WPAD + k] = w1.x; W1s[(cc + 1) * WPAD + k] = w1.y;
        W1s[(cc + 2) * WPAD + k] = w1.z; W1s[(cc + 3) * WPAD + k] = w1.w;
        W2s[(cc + 0) * WPAD + k] = w2.x; W2s[(cc + 1) * WPAD + k] = w2.y;
        W2s[(cc + 2) * WPAD + k] = w2.z; W2s[(cc + 3) * WPAD + k] = w2.w;
        W3s[(cc + 0) * WPAD + k] = w3.x; W3s[(cc + 1) * WPAD + k] = w3.y;
        W3s[(cc + 2) * WPAD + k] = w3.z; W3s[(cc + 3) * WPAD + k] = w3.w;
    }
    int c = tid & 63, w = tid >> 6;
    float b1c = b1[c], b3c = b3[c];
    float bsum = 0.f, bsq = 0.f;
    // act coeffs for the 4 channels this thread stages (idx = tid*4)
    int lc = (tid * 4) & 63;
    float4 sc4 = {1.f, 1.f, 1.f, 1.f}, sh4 = {0.f, 0.f, 0.f, 0.f};
    if (act) {
        float inv_n = 1.f / (float)N;
        bn_coeff(bsp, gamp, betp, lc + 0, inv_n, sc4.x, sh4.x);
        bn_coeff(bsp, gamp, betp, lc + 1, inv_n, sc4.y, sh4.y);
        bn_coeff(bsp, gamp, betp, lc + 2, inv_n, sc4.z, sh4.z);
        bn_coeff(bsp, gamp, betp, lc + 3, inv_n, sc4.w, sh4.w);
    }
    int wbase = c * WPAD;
    int numTiles = (N + 15) / 16;
    for (int tile = blockIdx.x; tile < numTiles; tile += gridDim.x) {
        int n0 = tile * 16;
        __syncthreads();
        {
            int idx = tid * 4;
            int nrow = idx >> 6;
            if (n0 + nrow < N) {
                int base = n0 * 64;
                *(float4*)&sS[idx] = *(const float4*)&S[base + idx];
                float4 v = *(const float4*)&h[base + idx];
                if (act) {
                    v.x = fmaxf(fmaf(v.x, sc4.x, sh4.x), 0.f);
                    v.y = fmaxf(fmaf(v.y, sc4.y, sh4.y), 0.f);
                    v.z = fmaxf(fmaf(v.z, sc4.z, sh4.z), 0.f);
                    v.w = fmaxf(fmaf(v.w, sc4.w, sh4.w), 0.f);
                }
                *(float4*)&sh[idx] = v;
            } else {
                sS[idx] = sS[idx + 1] = sS[idx + 2] = sS[idx + 3] = 0.f;
                sh[idx] = sh[idx + 1] = sh[idx + 2] = sh[idx + 3] = 0.f;
            }
            if (tid < 16) dwS[tid] = (n0 + tid < N) ? degw[n0 + tid] : 0.f;
        }
        __syncthreads();
        float aA[4] = {0, 0, 0, 0}, aB[4] = {0, 0, 0, 0}, aC[4] = {0, 0, 0, 0};
        for (int k = 0; k < 64; k += 4) {
            float4 w1 = *(const float4*)&W1s[wbase + k];  // per-lane b128
            float4 w2 = *(const float4*)&W2s[wbase + k];
            float4 w3 = *(const float4*)&W3s[wbase + k];
#pragma unroll
            for (int m = 0; m < 4; ++m) {
                int nl = w + 4 * m;
                float4 sv = *(const float4*)&sS[nl * 64 + k];  // broadcast b128
                float4 hv = *(const float4*)&sh[nl * 64 + k];
                aA[m] += sv.x * w1.x + sv.y * w1.y + sv.z * w1.z + sv.w * w1.w;
                aB[m] += hv.x * w2.x + hv.y * w2.y + hv.z * w2.z + hv.w * w2.w;
                aC[m] += hv.x * w3.x + hv.y * w3.y + hv.z * w3.z + hv.w * w3.w;
            }
        }
#pragma unroll
        for (int m = 0; m < 4; ++m) {
            int nl = w + 4 * m;
            int n = n0 + nl;
            if (n < N) {
                float dw = dwS[nl];
                float val = aA[m] + aC[m] - dw * aB[m] + dw * b1c + b3c;
                h[(size_t)n * 64 + c] = val;  // raw (pre-BN); tile already staged
                bsum += val;
                bsq += val * val;
            }
        }
    }
    __syncthreads();
    sS[tid] = bsum;
    sS[256 + tid] = bsq;
    __syncthreads();
    if (tid < 64) {
        float s = sS[tid] + sS[tid + 64] + sS[tid + 128] + sS[tid + 192];
        float q = sS[256 + tid] + sS[256 + tid + 64] + sS[256 + tid + 128] + sS[256 + tid + 192];
        atomicAdd(&bnstats[tid], s);
        atomicAdd(&bnstats[64 + tid], q);
    }
}

// ------- pool phase 1: per-graph sums of act(h_raw), sorted-run + atomics -------
#define POOL_TILE 128
__global__ __launch_bounds__(256) void k_poolsum(const float* __restrict__ h,
                                                 const int* __restrict__ batch,
                                                 const float* __restrict__ bsp,
                                                 const float* __restrict__ gamp,
                                                 const float* __restrict__ betp,
                                                 float* __restrict__ gsums, int N) {
    int tid = threadIdx.x;
    int c = tid & 63, q = tid >> 6;
    float sc, sh_;
    bn_coeff(bsp, gamp, betp, c, 1.f / (float)N, sc, sh_);
    int n0 = blockIdx.x * POOL_TILE;
    int nEnd = n0 + POOL_TILE; if (nEnd > N) nEnd = N;
    int g = -1;
    float acc = 0.f;
    for (int n = n0 + q; n < nEnd; n += 4) {
        int b = batch[n];
        if (b != g) {
            if (g >= 0) atomicAdd(&gsums[(size_t)g * 64 + c], acc);
            g = b; acc = 0.f;
        }
        acc += fmaxf(fmaf(h[(size_t)n * 64 + c], sc, sh_), 0.f);
    }
    if (g >= 0) atomicAdd(&gsums[(size_t)g * 64 + c], acc);
}

// ------- pool phase 2: divide by count + MLP head (one 64-thread block / graph) -
__global__ void k_head(const float* __restrict__ gsums, const int* __restrict__ batch,
                       const float* __restrict__ Wl1, const float* __restrict__ bl1,
                       const float* __restrict__ Wl2, const float* __restrict__ bl2,
                       float* __restrict__ out, int N) {
    int g = blockIdx.x;
    int c = threadIdx.x;  // 64 threads
    int lo = 0, hi = N;
    while (lo < hi) { int mid = (lo + hi) >> 1; if (batch[mid] < g) lo = mid + 1; else hi = mid; }
    int start = lo;
    hi = N;
    while (lo < hi) { int mid = (lo + hi) >> 1; if (batch[mid] < g + 1) lo = mid + 1; else hi = mid; }
    int cnt = lo - start;
    float denom = (float)(cnt > 0 ? cnt : 1);
    __shared__ float gS[64], yS[64];
    gS[c] = gsums[(size_t)g * 64 + c] / denom;
    __syncthreads();
    float y = bl1[c];
    for (int k = 0; k < 64; ++k) y += gS[k] * Wl1[k * 64 + c];
    yS[c] = fmaxf(y, 0.f);
    __syncthreads();
    if (c < 3) {
        float o = bl2[c];
        for (int k = 0; k < 64; ++k) o += yS[k] * Wl2[k * 3 + c];
        out[g * 3 + c] = o;
    }
}

extern "C" void kernel_launch(void* const* d_in, const int* in_sizes, int n_in,
                              void* d_out, int out_size, void* d_ws, size_t ws_size,
                              hipStream_t stream) {
    const float* x     = (const float*)d_in[0];
    const int*   eid   = (const int*)d_in[1];
    const float* attr  = (const float*)d_in[2];
    const int*   batch = (const int*)d_in[3];
    const float* Wemb  = (const float*)d_in[4];
    const float* bemb  = (const float*)d_in[5];
    const float* W1    = (const float*)d_in[6];
    const float* b1    = (const float*)d_in[7];
    const float* W2    = (const float*)d_in[8];
    const float* W3    = (const float*)d_in[9];
    const float* b3    = (const float*)d_in[10];
    const float* gamma = (const float*)d_in[11];
    const float* beta  = (const float*)d_in[12];
    const float* Wl1   = (const float*)d_in[13];
    const float* bl1   = (const float*)d_in[14];
    const float* Wl2   = (const float*)d_in[15];
    const float* bl2   = (const float*)d_in[16];

    int N = in_sizes[3];
    int E = in_sizes[2];
    int L = in_sizes[7] / 64;
    int G = out_size / 3;

    const int* src = eid;
    const int* dst = eid + E;

    float* ws      = (float*)d_ws;
    float* h       = ws;                       // N*64
    float* S       = h + (size_t)N * 64;       // N*64
    float* degw    = S + (size_t)N * 64;       // N
    float* bnstats = degw + N;                 // 3*128 (per-layer slots)
    float* gsums   = bnstats + 3 * 128;        // G*64
    int*   deg     = (int*)(gsums + (size_t)G * 64);  // N
    int*   rowptr  = deg + N;                  // N+2
    int*   bsum    = rowptr + (N + 2);         // 1024
    int*   gcur    = bsum + 1024;              // 1024 (bucket cursors)
    unsigned long long* edata = (unsigned long long*)(gcur + 1024);  // E
    unsigned long long* tmp   = edata + E;                           // E

    int nScanBlocks = (N + 1023) / 1024;
    int NB = (N + 255) >> 8;  // 256-node buckets (requires N < 2^24, NB <= 1024)

    // ---- CSR build + two-level counting sort of edges by dst ----
    hipMemsetAsync(deg, 0, (size_t)N * sizeof(int), stream);
    hipMemsetAsync(bnstats, 0, 3 * 128 * sizeof(float), stream);
    k_embed<<<(N * 64 + 255) / 256, 256, 0, stream>>>(x, Wemb, bemb, h, N);
    k_hist<<<(E + 255) / 256, 256, 0, stream>>>(dst, deg, E);
    k_blocksum<<<nScanBlocks, 256, 0, stream>>>(deg, bsum, N);
    k_scanpartials<<<1, 1024, 0, stream>>>(bsum, nScanBlocks);
    k_applyscan<<<nScanBlocks, 256, 0, stream>>>(deg, bsum, rowptr, N, E);
    k_initbcur<<<(NB + 255) / 256, 256, 0, stream>>>(rowptr, gcur, NB, N);
    k_binA<<<(E + ABLK - 1) / ABLK, 1024, 0, stream>>>(src, dst, attr, gcur, tmp, E, N);
    k_binB<<<NB, 256, 0, stream>>>(rowptr, tmp, edata, N);

    // ---- layers: split kernels, lazy BN, per-layer stats slots (no bnfinish) ----
    for (int l = 0; l < L; ++l) {
        int act = (l > 0) ? 1 : 0;
        const float* bsp  = bnstats + (size_t)(l > 0 ? l - 1 : 0) * 128;
        const float* gamp = gamma + (size_t)(l > 0 ? l - 1 : 0) * 64;
        const float* betp = beta + (size_t)(l > 0 ? l - 1 : 0) * 64;
        k_gather<<<(N * 64 + 255) / 256, 256, 0, stream>>>(
            rowptr, edata, h, bsp, gamp, betp, act, S, degw, N);
        k_update<<<512, 256, 0, stream>>>(S, h, degw, bsp, gamp, betp, act,
                                          W1 + (size_t)l * 4096, b1 + (size_t)l * 64,
                                          W2 + (size_t)l * 4096, W3 + (size_t)l * 4096,
                                          b3 + (size_t)l * 64, bnstats + (size_t)l * 128, N);
    }

    // ---- pool (applies final BN affine + relu lazily) + head ----
    hipMemsetAsync(gsums, 0, (size_t)G * 64 * sizeof(float), stream);
    k_poolsum<<<(N + POOL_TILE - 1) / POOL_TILE, 256, 0, stream>>>(
        h, batch, bnstats + (size_t)(L - 1) * 128, gamma + (size_t)(L - 1) * 64,
        beta + (size_t)(L - 1) * 64, gsums, N);
    k_head<<<G, 64, 0, stream>>>(gsums, batch, Wl1, bl1, Wl2, bl2, (float*)d_out, N);
}

// Round 15
// 596.765 us; speedup vs baseline: 1.0970x; 1.0970x over previous
//
#include <hip/hip_runtime.h>

#define BN_EPS 1e-5f

// ---------------- embedding: h = x @ W_emb + b_emb  (x is [N,4]) ----------------
__global__ void k_embed(const float* __restrict__ x, const float* __restrict__ Wemb,
                        const float* __restrict__ bemb, float* __restrict__ h, int N) {
    int t = blockIdx.x * blockDim.x + threadIdx.x;
    int n = t >> 6, c = t & 63;
    if (n >= N) return;
    const float* xr = x + (size_t)n * 4;
    float acc = bemb[c];
    acc += xr[0] * Wemb[0 * 64 + c];
    acc += xr[1] * Wemb[1 * 64 + c];
    acc += xr[2] * Wemb[2 * 64 + c];
    acc += xr[3] * Wemb[3 * 64 + c];
    h[t] = acc;
}

// ---------------- CSR build: histogram of dst ----------------
__global__ void k_hist(const int* __restrict__ dst, int* __restrict__ deg, int E) {
    int e = blockIdx.x * blockDim.x + threadIdx.x;
    if (e < E) atomicAdd(&deg[dst[e]], 1);
}

// ---------------- scan phase 1: per-block sums (1024 elems / 256-thread block) --
__global__ __launch_bounds__(256) void k_blocksum(const int* __restrict__ deg,
                                                  int* __restrict__ bsum, int N) {
    __shared__ int red[256];
    int tid = threadIdx.x;
    int base = blockIdx.x * 1024 + tid * 4;
    int s = 0;
    if (base + 3 < N) {
        int4 v = *(const int4*)&deg[base];
        s = v.x + v.y + v.z + v.w;
    } else {
        for (int i = 0; i < 4; ++i) if (base + i < N) s += deg[base + i];
    }
    red[tid] = s;
    __syncthreads();
    for (int d = 128; d > 0; d >>= 1) {
        if (tid < d) red[tid] += red[tid + d];
        __syncthreads();
    }
    if (tid == 0) bsum[blockIdx.x] = red[0];
}

// ---------------- scan phase 2: exclusive scan of block sums (nb <= 1024) -------
__global__ __launch_bounds__(1024) void k_scanpartials(int* __restrict__ bsum, int nb) {
    __shared__ int t[1024];
    int tid = threadIdx.x;
    int v = (tid < nb) ? bsum[tid] : 0;
    t[tid] = v;
    __syncthreads();
    for (int d = 1; d < 1024; d <<= 1) {
        int u = (tid >= d) ? t[tid - d] : 0;
        __syncthreads();
        t[tid] += u;
        __syncthreads();
    }
    if (tid < nb) bsum[tid] = t[tid] - v;  // exclusive
}

// ---- scan phase 3: per-block scan + offset, write rowptr (+ bucket cursors) ----
__global__ __launch_bounds__(256) void k_applyscan(const int* __restrict__ deg,
                                                   const int* __restrict__ bsum,
                                                   int* __restrict__ rowptr,
                                                   int* __restrict__ gcur, int N, int E) {
    __shared__ int red[256];
    int tid = threadIdx.x;
    int base = blockIdx.x * 1024 + tid * 4;
    int v0 = 0, v1 = 0, v2 = 0, v3 = 0;
    if (base + 3 < N) {
        int4 v = *(const int4*)&deg[base];
        v0 = v.x; v1 = v.y; v2 = v.z; v3 = v.w;
    } else {
        if (base < N) v0 = deg[base];
        if (base + 1 < N) v1 = deg[base + 1];
        if (base + 2 < N) v2 = deg[base + 2];
        if (base + 3 < N) v3 = deg[base + 3];
    }
    int s = v0 + v1 + v2 + v3;
    red[tid] = s;
    __syncthreads();
    for (int d = 1; d < 256; d <<= 1) {
        int u = (tid >= d) ? red[tid - d] : 0;
        __syncthreads();
        red[tid] += u;
        __syncthreads();
    }
    int off = bsum[blockIdx.x] + red[tid] - s;
    int r0 = off, r1 = off + v0, r2 = r1 + v1, r3 = r2 + v2;
    if (base < N)     rowptr[base] = r0;
    if (base + 1 < N) rowptr[base + 1] = r1;
    if (base + 2 < N) rowptr[base + 2] = r2;
    if (base + 3 < N) rowptr[base + 3] = r3;
    if ((base & 255) == 0 && base < N) gcur[base >> 8] = r0;  // fused k_initbcur
    if (blockIdx.x == 0 && tid == 0) rowptr[N] = E;
}

// ------- sort pass A: partition edges into 256-node buckets (requires N < 2^24) -
#define ABLK 8192
__global__ __launch_bounds__(1024) void k_binA(const int* __restrict__ src,
                                               const int* __restrict__ dst,
                                               const float* __restrict__ attr,
                                               int* __restrict__ gcur,
                                               unsigned long long* __restrict__ tmp,
                                               int E, int N) {
    __shared__ int hist[1024];
    __shared__ int lcur[1024];
    int tid = threadIdx.x;
    int NB = (N + 255) >> 8;  // <= 1024 for N <= 262144
    int e0 = blockIdx.x * ABLK;
    int e1 = e0 + ABLK; if (e1 > E) e1 = E;
    for (int i = tid; i < NB; i += 1024) hist[i] = 0;
    __syncthreads();
    for (int e = e0 + tid; e < e1; e += 1024) atomicAdd(&hist[dst[e] >> 8], 1);
    __syncthreads();
    for (int b = tid; b < NB; b += 1024) {
        int hc = hist[b];
        lcur[b] = hc ? atomicAdd(&gcur[b], hc) : 0;
    }
    __syncthreads();
    for (int e = e0 + tid; e < e1; e += 1024) {
        int d = dst[e];
        int pos = atomicAdd(&lcur[d >> 8], 1);
        unsigned long long p = ((unsigned long long)__float_as_uint(attr[e]) << 32) |
                               ((unsigned long long)(d & 255) << 24) |
                               (unsigned int)src[e];
        tmp[pos] = p;
    }
}

// ------- sort pass B: one block per bucket; exact node placement via LDS cursors.
__global__ __launch_bounds__(256) void k_binB(const int* __restrict__ rowptr,
                                              const unsigned long long* __restrict__ tmp,
                                              unsigned long long* __restrict__ edata,
                                              int N) {
    __shared__ int cur[256];
    int b = blockIdx.x;
    int tid = threadIdx.x;
    int nb0 = b << 8;
    int node = nb0 + tid;
    cur[tid] = (node < N) ? rowptr[node] : 0;
    int beg = rowptr[nb0];
    int endnode = nb0 + 256; if (endnode > N) endnode = N;
    int end = rowptr[endnode];
    __syncthreads();
    for (int e = beg + tid; e < end; e += 256) {
        unsigned long long p = tmp[e];
        int dl = (int)((p >> 24) & 255);
        int pos = atomicAdd(&cur[dl], 1);
        edata[pos] = p & 0xFFFFFFFF00FFFFFFull;  // clear dstlow: [attr | src]
    }
}

// ---- inline BN scale/shift from raw stats (replaces the k_bnfinish kernel) ----
__device__ __forceinline__ void bn_coeff(const float* bs, const float* gam,
                                         const float* bet, int c, float inv_n,
                                         float& sc, float& sh) {
    float mean = bs[c] * inv_n;
    float var = bs[64 + c] * inv_n - mean * mean;
    sc = gam[c] * rsqrtf(fmaxf(var, 0.f) + BN_EPS);
    sh = bet[c] - mean * sc;
}

// ------- pull gather with lazy BN: S[n] = sum_e w_e * act(h_raw[src_e]) --------
__global__ void k_gather(const int* __restrict__ rowptr,
                         const unsigned long long* __restrict__ edata,
                         const float* __restrict__ h,
                         const float* __restrict__ bsp, const float* __restrict__ gamp,
                         const float* __restrict__ betp, int act,
                         float* __restrict__ S, float* __restrict__ degw, int N) {
    int t = blockIdx.x * blockDim.x + threadIdx.x;
    int n = t >> 6, c = t & 63;
    if (n >= N) return;
    float sc = 1.f, sh = 0.f;
    if (act) bn_coeff(bsp, gamp, betp, c, 1.f / (float)N, sc, sh);
    int beg = rowptr[n], end = rowptr[n + 1];
    int len = end - beg;
    float acc[8] = {0.f, 0.f, 0.f, 0.f, 0.f, 0.f, 0.f, 0.f};
    float wsum = 0.f;
    for (int base = 0; base < len; base += 8) {
#pragma unroll
        for (int i = 0; i < 8; ++i) {
            int idx = base + i;
            int ce = beg + (idx < len ? idx : len - 1);  // wave-uniform predicate
            unsigned long long p = edata[ce];
            float w = (idx < len) ? __uint_as_float((unsigned int)(p >> 32)) : 0.f;
            int s = (int)(unsigned int)p;
            float v = h[(size_t)s * 64 + c];
            if (act) v = fmaxf(fmaf(v, sc, sh), 0.f);
            acc[i] += w * v;
            wsum += w;
        }
    }
    float r = ((acc[0] + acc[1]) + (acc[2] + acc[3])) +
              ((acc[4] + acc[5]) + (acc[6] + acc[7]));
    S[(size_t)n * 64 + c] = r;
    if (c == 0) degw[n] = wsum;
}

// --- h_raw_out = S@W1 + x@W3 - dw*(x@W2) + dw*b1 + b3 (in place, x=act(h_raw));
// R10-proven b32 inner loop (readlane/s_load/b128-transpose all regressed — do
// not revisit). This round: 512-thread blocks + 32-row tiles. Weights (48KB) +
// tiles (16.5KB) = 64.7KB -> still 2 blocks/CU but 16 waves/CU (vs 8), doubling
// LDS+VALU issue pressure on the LDS-issue-bound loop; staging amortized 2x.
__global__ __launch_bounds__(512) void k_update(
    const float* __restrict__ S, float* __restrict__ h,
    const float* __restrict__ degw,
    const float* __restrict__ bsp, const float* __restrict__ gamp,
    const float* __restrict__ betp, int act,
    const float* __restrict__ W1, const float* __restrict__ b1,
    const float* __restrict__ W2, const float* __restrict__ W3,
    const float* __restrict__ b3,
    float* __restrict__ bnstats, int N) {
    __shared__ float W1s[64 * 64], W2s[64 * 64], W3s[64 * 64];
    __shared__ float sS[32 * 64], sh[32 * 64];
    __shared__ float dwS[32];
    int tid = threadIdx.x;
    for (int i = tid * 4; i < 4096; i += 2048) {
        *(float4*)&W1s[i] = *(const float4*)&W1[i];
        *(float4*)&W2s[i] = *(const float4*)&W2[i];
        *(float4*)&W3s[i] = *(const float4*)&W3[i];
    }
    int c = tid & 63, w = tid >> 6;  // 8 waves; wave w handles rows w+8m, m=0..3
    float b1c = b1[c], b3c = b3[c];
    float bsum = 0.f, bsq = 0.f;
    // act coeffs for the 4 channels this thread stages (idx = tid*4)
    int lc = (tid * 4) & 63;
    float4 sc4 = {1.f, 1.f, 1.f, 1.f}, sh4 = {0.f, 0.f, 0.f, 0.f};
    if (act) {
        float inv_n = 1.f / (float)N;
        bn_coeff(bsp, gamp, betp, lc + 0, inv_n, sc4.x, sh4.x);
        bn_coeff(bsp, gamp, betp, lc + 1, inv_n, sc4.y, sh4.y);
        bn_coeff(bsp, gamp, betp, lc + 2, inv_n, sc4.z, sh4.z);
        bn_coeff(bsp, gamp, betp, lc + 3, inv_n, sc4.w, sh4.w);
    }
    int numTiles = (N + 31) / 32;
    for (int tile = blockIdx.x; tile < numTiles; tile += gridDim.x) {
        int n0 = tile * 32;
        __syncthreads();
        {
            int idx = tid * 4;           // 2048 floats per tile array
            int nrow = idx >> 6;
            if (n0 + nrow < N) {
                int base = n0 * 64;
                *(float4*)&sS[idx] = *(const float4*)&S[base + idx];
                float4 v = *(const float4*)&h[base + idx];
                if (act) {
                    v.x = fmaxf(fmaf(v.x, sc4.x, sh4.x), 0.f);
                    v.y = fmaxf(fmaf(v.y, sc4.y, sh4.y), 0.f);
                    v.z = fmaxf(fmaf(v.z, sc4.z, sh4.z), 0.f);
                    v.w = fmaxf(fmaf(v.w, sc4.w, sh4.w), 0.f);
                }
                *(float4*)&sh[idx] = v;
            } else {
                sS[idx] = sS[idx + 1] = sS[idx + 2] = sS[idx + 3] = 0.f;
                sh[idx] = sh[idx + 1] = sh[idx + 2] = sh[idx + 3] = 0.f;
            }
            if (tid < 32) dwS[tid] = (n0 + tid < N) ? degw[n0 + tid] : 0.f;
        }
        __syncthreads();
        float aA[4] = {0, 0, 0, 0}, aB[4] = {0, 0, 0, 0}, aC[4] = {0, 0, 0, 0};
        for (int k = 0; k < 64; ++k) {
            float w1 = W1s[k * 64 + c], w2 = W2s[k * 64 + c], w3 = W3s[k * 64 + c];
#pragma unroll
            for (int m = 0; m < 4; ++m) {
                int nl = w + 8 * m;
                float sv = sS[nl * 64 + k], hv = sh[nl * 64 + k];
                aA[m] += sv * w1;
                aB[m] += hv * w2;
                aC[m] += hv * w3;
            }
        }
#pragma unroll
        for (int m = 0; m < 4; ++m) {
            int nl = w + 8 * m;
            int n = n0 + nl;
            if (n < N) {
                float dw = dwS[nl];
                float val = aA[m] + aC[m] - dw * aB[m] + dw * b1c + b3c;
                h[(size_t)n * 64 + c] = val;  // raw (pre-BN); tile already staged
                bsum += val;
                bsq += val * val;
            }
        }
    }
    // ---- BN stats reduction (reuse sS: needs 1024 floats) ----
    __syncthreads();
    sS[tid] = bsum;
    sS[512 + tid] = bsq;
    __syncthreads();
    if (tid < 64) {
        float s = 0.f, q = 0.f;
#pragma unroll
        for (int i = 0; i < 8; ++i) {
            s += sS[tid + i * 64];
            q += sS[512 + tid + i * 64];
        }
        atomicAdd(&bnstats[tid], s);
        atomicAdd(&bnstats[64 + tid], q);
    }
}

// ------- pool phase 1: per-graph sums of act(h_raw), sorted-run + atomics -------
#define POOL_TILE 128
__global__ __launch_bounds__(256) void k_poolsum(const float* __restrict__ h,
                                                 const int* __restrict__ batch,
                                                 const float* __restrict__ bsp,
                                                 const float* __restrict__ gamp,
                                                 const float* __restrict__ betp,
                                                 float* __restrict__ gsums, int N) {
    int tid = threadIdx.x;
    int c = tid & 63, q = tid >> 6;
    float sc, sh_;
    bn_coeff(bsp, gamp, betp, c, 1.f / (float)N, sc, sh_);
    int n0 = blockIdx.x * POOL_TILE;
    int nEnd = n0 + POOL_TILE; if (nEnd > N) nEnd = N;
    int g = -1;
    float acc = 0.f;
    for (int n = n0 + q; n < nEnd; n += 4) {
        int b = batch[n];
        if (b != g) {
            if (g >= 0) atomicAdd(&gsums[(size_t)g * 64 + c], acc);
            g = b; acc = 0.f;
        }
        acc += fmaxf(fmaf(h[(size_t)n * 64 + c], sc, sh_), 0.f);
    }
    if (g >= 0) atomicAdd(&gsums[(size_t)g * 64 + c], acc);
}

// ------- pool phase 2: divide by count + MLP head (one 64-thread block / graph) -
__global__ void k_head(const float* __restrict__ gsums, const int* __restrict__ batch,
                       const float* __restrict__ Wl1, const float* __restrict__ bl1,
                       const float* __restrict__ Wl2, const float* __restrict__ bl2,
                       float* __restrict__ out, int N) {
    int g = blockIdx.x;
    int c = threadIdx.x;  // 64 threads
    int lo = 0, hi = N;
    while (lo < hi) { int mid = (lo + hi) >> 1; if (batch[mid] < g) lo = mid + 1; else hi = mid; }
    int start = lo;
    hi = N;
    while (lo < hi) { int mid = (lo + hi) >> 1; if (batch[mid] < g + 1) lo = mid + 1; else hi = mid; }
    int cnt = lo - start;
    float denom = (float)(cnt > 0 ? cnt : 1);
    __shared__ float gS[64], yS[64];
    gS[c] = gsums[(size_t)g * 64 + c] / denom;
    __syncthreads();
    float y = bl1[c];
    for (int k = 0; k < 64; ++k) y += gS[k] * Wl1[k * 64 + c];
    yS[c] = fmaxf(y, 0.f);
    __syncthreads();
    if (c < 3) {
        float o = bl2[c];
        for (int k = 0; k < 64; ++k) o += yS[k] * Wl2[k * 3 + c];
        out[g * 3 + c] = o;
    }
}

extern "C" void kernel_launch(void* const* d_in, const int* in_sizes, int n_in,
                              void* d_out, int out_size, void* d_ws, size_t ws_size,
                              hipStream_t stream) {
    const float* x     = (const float*)d_in[0];
    const int*   eid   = (const int*)d_in[1];
    const float* attr  = (const float*)d_in[2];
    const int*   batch = (const int*)d_in[3];
    const float* Wemb  = (const float*)d_in[4];
    const float* bemb  = (const float*)d_in[5];
    const float* W1    = (const float*)d_in[6];
    const float* b1    = (const float*)d_in[7];
    const float* W2    = (const float*)d_in[8];
    const float* W3    = (const float*)d_in[9];
    const float* b3    = (const float*)d_in[10];
    const float* gamma = (const float*)d_in[11];
    const float* beta  = (const float*)d_in[12];
    const float* Wl1   = (const float*)d_in[13];
    const float* bl1   = (const float*)d_in[14];
    const float* Wl2   = (const float*)d_in[15];
    const float* bl2   = (const float*)d_in[16];

    int N = in_sizes[3];
    int E = in_sizes[2];
    int L = in_sizes[7] / 64;
    int G = out_size / 3;

    const int* src = eid;
    const int* dst = eid + E;

    float* ws      = (float*)d_ws;
    float* h       = ws;                       // N*64
    float* S       = h + (size_t)N * 64;       // N*64
    float* degw    = S + (size_t)N * 64;       // N
    float* bnstats = degw + N;                 // 3*128 (per-layer slots)
    float* gsums   = bnstats + 3 * 128;        // G*64
    int*   deg     = (int*)(gsums + (size_t)G * 64);  // N
    int*   rowptr  = deg + N;                  // N+2
    int*   bsum    = rowptr + (N + 2);         // 1024
    int*   gcur    = bsum + 1024;              // 1024 (bucket cursors)
    unsigned long long* edata = (unsigned long long*)(gcur + 1024);  // E
    unsigned long long* tmp   = edata + E;                           // E

    int nScanBlocks = (N + 1023) / 1024;
    int NB = (N + 255) >> 8;  // 256-node buckets (requires N < 2^24, NB <= 1024)

    // ---- CSR build + two-level counting sort of edges by dst ----
    hipMemsetAsync(deg, 0, (size_t)N * sizeof(int), stream);
    hipMemsetAsync(bnstats, 0, 3 * 128 * sizeof(float), stream);
    k_embed<<<(N * 64 + 255) / 256, 256, 0, stream>>>(x, Wemb, bemb, h, N);
    k_hist<<<(E + 255) / 256, 256, 0, stream>>>(dst, deg, E);
    k_blocksum<<<nScanBlocks, 256, 0, stream>>>(deg, bsum, N);
    k_scanpartials<<<1, 1024, 0, stream>>>(bsum, nScanBlocks);
    k_applyscan<<<nScanBlocks, 256, 0, stream>>>(deg, bsum, rowptr, gcur, N, E);
    k_binA<<<(E + ABLK - 1) / ABLK, 1024, 0, stream>>>(src, dst, attr, gcur, tmp, E, N);
    k_binB<<<NB, 256, 0, stream>>>(rowptr, tmp, edata, N);

    // ---- layers: split kernels, lazy BN, per-layer stats slots (no bnfinish) ----
    for (int l = 0; l < L; ++l) {
        int act = (l > 0) ? 1 : 0;
        const float* bsp  = bnstats + (size_t)(l > 0 ? l - 1 : 0) * 128;
        const float* gamp = gamma + (size_t)(l > 0 ? l - 1 : 0) * 64;
        const float* betp = beta + (size_t)(l > 0 ? l - 1 : 0) * 64;
        k_gather<<<(N * 64 + 255) / 256, 256, 0, stream>>>(
            rowptr, edata, h, bsp, gamp, betp, act, S, degw, N);
        k_update<<<512, 512, 0, stream>>>(S, h, degw, bsp, gamp, betp, act,
                                          W1 + (size_t)l * 4096, b1 + (size_t)l * 64,
                                          W2 + (size_t)l * 4096, W3 + (size_t)l * 4096,
                                          b3 + (size_t)l * 64, bnstats + (size_t)l * 128, N);
    }

    // ---- pool (applies final BN affine + relu lazily) + head ----
    hipMemsetAsync(gsums, 0, (size_t)G * 64 * sizeof(float), stream);
    k_poolsum<<<(N + POOL_TILE - 1) / POOL_TILE, 256, 0, stream>>>(
        h, batch, bnstats + (size_t)(L - 1) * 128, gamma + (size_t)(L - 1) * 64,
        beta + (size_t)(L - 1) * 64, gsums, N);
    k_head<<<G, 64, 0, stream>>>(gsums, batch, Wl1, bl1, Wl2, bl2, (float*)d_out, N);
}

// Round 16
// 592.565 us; speedup vs baseline: 1.1048x; 1.0071x over previous
//
#include <hip/hip_runtime.h>

#define BN_EPS 1e-5f

// ---------------- embedding: h = x @ W_emb + b_emb  (x is [N,4]) ----------------
__global__ void k_embed(const float* __restrict__ x, const float* __restrict__ Wemb,
                        const float* __restrict__ bemb, float* __restrict__ h, int N) {
    int t = blockIdx.x * blockDim.x + threadIdx.x;
    int n = t >> 6, c = t & 63;
    if (n >= N) return;
    const float* xr = x + (size_t)n * 4;
    float acc = bemb[c];
    acc += xr[0] * Wemb[0 * 64 + c];
    acc += xr[1] * Wemb[1 * 64 + c];
    acc += xr[2] * Wemb[2 * 64 + c];
    acc += xr[3] * Wemb[3 * 64 + c];
    h[t] = acc;
}

// ---------------- CSR build: histogram of dst ----------------
__global__ void k_hist(const int* __restrict__ dst, int* __restrict__ deg, int E) {
    int e = blockIdx.x * blockDim.x + threadIdx.x;
    if (e < E) atomicAdd(&deg[dst[e]], 1);
}

// ---------------- scan phase 1: per-block sums (1024 elems / 256-thread block) --
__global__ __launch_bounds__(256) void k_blocksum(const int* __restrict__ deg,
                                                  int* __restrict__ bsum, int N) {
    __shared__ int red[256];
    int tid = threadIdx.x;
    int base = blockIdx.x * 1024 + tid * 4;
    int s = 0;
    if (base + 3 < N) {
        int4 v = *(const int4*)&deg[base];
        s = v.x + v.y + v.z + v.w;
    } else {
        for (int i = 0; i < 4; ++i) if (base + i < N) s += deg[base + i];
    }
    red[tid] = s;
    __syncthreads();
    for (int d = 128; d > 0; d >>= 1) {
        if (tid < d) red[tid] += red[tid + d];
        __syncthreads();
    }
    if (tid == 0) bsum[blockIdx.x] = red[0];
}

// ---------------- scan phase 2: exclusive scan of block sums (nb <= 1024) -------
__global__ __launch_bounds__(1024) void k_scanpartials(int* __restrict__ bsum, int nb) {
    __shared__ int t[1024];
    int tid = threadIdx.x;
    int v = (tid < nb) ? bsum[tid] : 0;
    t[tid] = v;
    __syncthreads();
    for (int d = 1; d < 1024; d <<= 1) {
        int u = (tid >= d) ? t[tid - d] : 0;
        __syncthreads();
        t[tid] += u;
        __syncthreads();
    }
    if (tid < nb) bsum[tid] = t[tid] - v;  // exclusive
}

// ---- scan phase 3: per-block scan + offset, write rowptr (+ bucket cursors) ----
__global__ __launch_bounds__(256) void k_applyscan(const int* __restrict__ deg,
                                                   const int* __restrict__ bsum,
                                                   int* __restrict__ rowptr,
                                                   int* __restrict__ gcur, int N, int E) {
    __shared__ int red[256];
    int tid = threadIdx.x;
    int base = blockIdx.x * 1024 + tid * 4;
    int v0 = 0, v1 = 0, v2 = 0, v3 = 0;
    if (base + 3 < N) {
        int4 v = *(const int4*)&deg[base];
        v0 = v.x; v1 = v.y; v2 = v.z; v3 = v.w;
    } else {
        if (base < N) v0 = deg[base];
        if (base + 1 < N) v1 = deg[base + 1];
        if (base + 2 < N) v2 = deg[base + 2];
        if (base + 3 < N) v3 = deg[base + 3];
    }
    int s = v0 + v1 + v2 + v3;
    red[tid] = s;
    __syncthreads();
    for (int d = 1; d < 256; d <<= 1) {
        int u = (tid >= d) ? red[tid - d] : 0;
        __syncthreads();
        red[tid] += u;
        __syncthreads();
    }
    int off = bsum[blockIdx.x] + red[tid] - s;
    int r0 = off, r1 = off + v0, r2 = r1 + v1, r3 = r2 + v2;
    if (base < N)     rowptr[base] = r0;
    if (base + 1 < N) rowptr[base + 1] = r1;
    if (base + 2 < N) rowptr[base + 2] = r2;
    if (base + 3 < N) rowptr[base + 3] = r3;
    if ((base & 255) == 0 && base < N) gcur[base >> 8] = r0;  // fused k_initbcur
    if (blockIdx.x == 0 && tid == 0) rowptr[N] = E;
}

// ------- sort pass A: partition edges into 256-node buckets (requires N < 2^24) -
#define ABLK 8192
__global__ __launch_bounds__(1024) void k_binA(const int* __restrict__ src,
                                               const int* __restrict__ dst,
                                               const float* __restrict__ attr,
                                               int* __restrict__ gcur,
                                               unsigned long long* __restrict__ tmp,
                                               int E, int N) {
    __shared__ int hist[1024];
    __shared__ int lcur[1024];
    int tid = threadIdx.x;
    int NB = (N + 255) >> 8;  // <= 1024 for N <= 262144
    int e0 = blockIdx.x * ABLK;
    int e1 = e0 + ABLK; if (e1 > E) e1 = E;
    for (int i = tid; i < NB; i += 1024) hist[i] = 0;
    __syncthreads();
    for (int e = e0 + tid; e < e1; e += 1024) atomicAdd(&hist[dst[e] >> 8], 1);
    __syncthreads();
    for (int b = tid; b < NB; b += 1024) {
        int hc = hist[b];
        lcur[b] = hc ? atomicAdd(&gcur[b], hc) : 0;
    }
    __syncthreads();
    for (int e = e0 + tid; e < e1; e += 1024) {
        int d = dst[e];
        int pos = atomicAdd(&lcur[d >> 8], 1);
        unsigned long long p = ((unsigned long long)__float_as_uint(attr[e]) << 32) |
                               ((unsigned long long)(d & 255) << 24) |
                               (unsigned int)src[e];
        tmp[pos] = p;
    }
}

// ------- sort pass B: one block per bucket; exact node placement via LDS cursors.
// Final edata word: [attr:32 | src*256:32] (byte offset of the h row).
__global__ __launch_bounds__(256) void k_binB(const int* __restrict__ rowptr,
                                              const unsigned long long* __restrict__ tmp,
                                              unsigned long long* __restrict__ edata,
                                              int N) {
    __shared__ int cur[256];
    int b = blockIdx.x;
    int tid = threadIdx.x;
    int nb0 = b << 8;
    int node = nb0 + tid;
    cur[tid] = (node < N) ? rowptr[node] : 0;
    int beg = rowptr[nb0];
    int endnode = nb0 + 256; if (endnode > N) endnode = N;
    int end = rowptr[endnode];
    __syncthreads();
    for (int e = beg + tid; e < end; e += 256) {
        unsigned long long p = tmp[e];
        int dl = (int)((p >> 24) & 255);
        int pos = atomicAdd(&cur[dl], 1);
        edata[pos] = (p & 0xFFFFFFFF00000000ull) | ((p & 0xFFFFFFull) << 8);
    }
}

// ---- inline BN scale/shift from raw stats (replaces the k_bnfinish kernel) ----
__device__ __forceinline__ void bn_coeff(const float* bs, const float* gam,
                                         const float* bet, int c, float inv_n,
                                         float& sc, float& sh) {
    float mean = bs[c] * inv_n;
    float var = bs[64 + c] * inv_n - mean * mean;
    sc = gam[c] * rsqrtf(fmaxf(var, 0.f) + BN_EPS);
    sh = bet[c] - mean * sc;
}

// ------- pull gather with lazy BN: S[n] = sum_e w_e * act(h_raw[src_e]) --------
// Two-phase loop: unmasked full 8-groups (no cmp/cndmask) + one masked tail
// group. edata's low 32 bits are the h-row BYTE offset (src*256) -> address is
// one v_or + saddr load. degw is edge-structure-invariant: computed/stored only
// at layer 0 (SAVEDW=1); later layers drop the wsum chain entirely.
template <int ACT, int SAVEDW>
__global__ void k_gather(const int* __restrict__ rowptr,
                         const unsigned long long* __restrict__ edata,
                         const float* __restrict__ h,
                         const float* __restrict__ bsp, const float* __restrict__ gamp,
                         const float* __restrict__ betp,
                         float* __restrict__ S, float* __restrict__ degw, int N) {
    int t = blockIdx.x * blockDim.x + threadIdx.x;
    int n = t >> 6, c = t & 63;
    if (n >= N) return;
    unsigned c4 = (unsigned)(c << 2);
    float sc = 1.f, sh = 0.f;
    if (ACT) bn_coeff(bsp, gamp, betp, c, 1.f / (float)N, sc, sh);
    int beg = rowptr[n], end = rowptr[n + 1];
    int len = end - beg;
    float acc[8] = {0.f, 0.f, 0.f, 0.f, 0.f, 0.f, 0.f, 0.f};
    float wsum = 0.f;
    int nFull = len & ~7;
    for (int base = 0; base < nFull; base += 8) {
#pragma unroll
        for (int i = 0; i < 8; ++i) {
            unsigned long long p = edata[beg + base + i];
            float w = __uint_as_float((unsigned)(p >> 32));
            unsigned off = (unsigned)p;  // src*256
            float v = *(const float*)((const char*)h + (off | c4));
            if (ACT) v = fmaxf(fmaf(v, sc, sh), 0.f);
            acc[i] += w * v;
            if (SAVEDW) wsum += w;
        }
    }
    if (nFull < len) {
#pragma unroll
        for (int i = 0; i < 8; ++i) {
            int idx = nFull + i;
            int ce = beg + (idx < len ? idx : len - 1);
            unsigned long long p = edata[ce];
            float w = (idx < len) ? __uint_as_float((unsigned)(p >> 32)) : 0.f;
            unsigned off = (unsigned)p;
            float v = *(const float*)((const char*)h + (off | c4));
            if (ACT) v = fmaxf(fmaf(v, sc, sh), 0.f);
            acc[i] += w * v;
            if (SAVEDW) wsum += w;
        }
    }
    float r = ((acc[0] + acc[1]) + (acc[2] + acc[3])) +
              ((acc[4] + acc[5]) + (acc[6] + acc[7]));
    S[(size_t)n * 64 + c] = r;
    if (SAVEDW && c == 0) degw[n] = wsum;
}

// --- h_raw_out = S@W1 + x@W3 - dw*(x@W2) + dw*b1 + b3 (in place, x=act(h_raw));
// R10-proven b32 inner loop (readlane/s_load/b128-transpose all regressed -- do
// not revisit). 512-thread blocks + 32-row tiles: weights (48KB) + tiles
// (16.5KB) = 64.7KB -> 2 blocks/CU, 16 waves/CU (proven R15 win).
__global__ __launch_bounds__(512) void k_update(
    const float* __restrict__ S, float* __restrict__ h,
    const float* __restrict__ degw,
    const float* __restrict__ bsp, const float* __restrict__ gamp,
    const float* __restrict__ betp, int act,
    const float* __restrict__ W1, const float* __restrict__ b1,
    const float* __restrict__ W2, const float* __restrict__ W3,
    const float* __restrict__ b3,
    float* __restrict__ bnstats, int N) {
    __shared__ float W1s[64 * 64], W2s[64 * 64], W3s[64 * 64];
    __shared__ float sS[32 * 64], sh[32 * 64];
    __shared__ float dwS[32];
    int tid = threadIdx.x;
    for (int i = tid * 4; i < 4096; i += 2048) {
        *(float4*)&W1s[i] = *(const float4*)&W1[i];
        *(float4*)&W2s[i] = *(const float4*)&W2[i];
        *(float4*)&W3s[i] = *(const float4*)&W3[i];
    }
    int c = tid & 63, w = tid >> 6;  // 8 waves; wave w handles rows w+8m, m=0..3
    float b1c = b1[c], b3c = b3[c];
    float bsum = 0.f, bsq = 0.f;
    int lc = (tid * 4) & 63;
    float4 sc4 = {1.f, 1.f, 1.f, 1.f}, sh4 = {0.f, 0.f, 0.f, 0.f};
    if (act) {
        float inv_n = 1.f / (float)N;
        bn_coeff(bsp, gamp, betp, lc + 0, inv_n, sc4.x, sh4.x);
        bn_coeff(bsp, gamp, betp, lc + 1, inv_n, sc4.y, sh4.y);
        bn_coeff(bsp, gamp, betp, lc + 2, inv_n, sc4.z, sh4.z);
        bn_coeff(bsp, gamp, betp, lc + 3, inv_n, sc4.w, sh4.w);
    }
    int numTiles = (N + 31) / 32;
    for (int tile = blockIdx.x; tile < numTiles; tile += gridDim.x) {
        int n0 = tile * 32;
        __syncthreads();
        {
            int idx = tid * 4;
            int nrow = idx >> 6;
            if (n0 + nrow < N) {
                int base = n0 * 64;
                *(float4*)&sS[idx] = *(const float4*)&S[base + idx];
                float4 v = *(const float4*)&h[base + idx];
                if (act) {
                    v.x = fmaxf(fmaf(v.x, sc4.x, sh4.x), 0.f);
                    v.y = fmaxf(fmaf(v.y, sc4.y, sh4.y), 0.f);
                    v.z = fmaxf(fmaf(v.z, sc4.z, sh4.z), 0.f);
                    v.w = fmaxf(fmaf(v.w, sc4.w, sh4.w), 0.f);
                }
                *(float4*)&sh[idx] = v;
            } else {
                sS[idx] = sS[idx + 1] = sS[idx + 2] = sS[idx + 3] = 0.f;
                sh[idx] = sh[idx + 1] = sh[idx + 2] = sh[idx + 3] = 0.f;
            }
            if (tid < 32) dwS[tid] = (n0 + tid < N) ? degw[n0 + tid] : 0.f;
        }
        __syncthreads();
        float aA[4] = {0, 0, 0, 0}, aB[4] = {0, 0, 0, 0}, aC[4] = {0, 0, 0, 0};
        for (int k = 0; k < 64; ++k) {
            float w1 = W1s[k * 64 + c], w2 = W2s[k * 64 + c], w3 = W3s[k * 64 + c];
#pragma unroll
            for (int m = 0; m < 4; ++m) {
                int nl = w + 8 * m;
                float sv = sS[nl * 64 + k], hv = sh[nl * 64 + k];
                aA[m] += sv * w1;
                aB[m] += hv * w2;
                aC[m] += hv * w3;
            }
        }
#pragma unroll
        for (int m = 0; m < 4; ++m) {
            int nl = w + 8 * m;
            int n = n0 + nl;
            if (n < N) {
                float dw = dwS[nl];
                float val = aA[m] + aC[m] - dw * aB[m] + dw * b1c + b3c;
                h[(size_t)n * 64 + c] = val;  // raw (pre-BN); tile already staged
                bsum += val;
                bsq += val * val;
            }
        }
    }
    // ---- BN stats reduction (reuse sS: needs 1024 floats) ----
    __syncthreads();
    sS[tid] = bsum;
    sS[512 + tid] = bsq;
    __syncthreads();
    if (tid < 64) {
        float s = 0.f, q = 0.f;
#pragma unroll
        for (int i = 0; i < 8; ++i) {
            s += sS[tid + i * 64];
            q += sS[512 + tid + i * 64];
        }
        atomicAdd(&bnstats[tid], s);
        atomicAdd(&bnstats[64 + tid], q);
    }
}

// ------- pool phase 1: per-graph sums of act(h_raw), sorted-run + atomics -------
#define POOL_TILE 128
__global__ __launch_bounds__(256) void k_poolsum(const float* __restrict__ h,
                                                 const int* __restrict__ batch,
                                                 const float* __restrict__ bsp,
                                                 const float* __restrict__ gamp,
                                                 const float* __restrict__ betp,
                                                 float* __restrict__ gsums, int N) {
    int tid = threadIdx.x;
    int c = tid & 63, q = tid >> 6;
    float sc, sh_;
    bn_coeff(bsp, gamp, betp, c, 1.f / (float)N, sc, sh_);
    int n0 = blockIdx.x * POOL_TILE;
    int nEnd = n0 + POOL_TILE; if (nEnd > N) nEnd = N;
    int g = -1;
    float acc = 0.f;
    for (int n = n0 + q; n < nEnd; n += 4) {
        int b = batch[n];
        if (b != g) {
            if (g >= 0) atomicAdd(&gsums[(size_t)g * 64 + c], acc);
            g = b; acc = 0.f;
        }
        acc += fmaxf(fmaf(h[(size_t)n * 64 + c], sc, sh_), 0.f);
    }
    if (g >= 0) atomicAdd(&gsums[(size_t)g * 64 + c], acc);
}

// ------- pool phase 2: divide by count + MLP head (one 64-thread block / graph) -
__global__ void k_head(const float* __restrict__ gsums, const int* __restrict__ batch,
                       const float* __restrict__ Wl1, const float* __restrict__ bl1,
                       const float* __restrict__ Wl2, const float* __restrict__ bl2,
                       float* __restrict__ out, int N) {
    int g = blockIdx.x;
    int c = threadIdx.x;  // 64 threads
    int lo = 0, hi = N;
    while (lo < hi) { int mid = (lo + hi) >> 1; if (batch[mid] < g) lo = mid + 1; else hi = mid; }
    int start = lo;
    hi = N;
    while (lo < hi) { int mid = (lo + hi) >> 1; if (batch[mid] < g + 1) lo = mid + 1; else hi = mid; }
    int cnt = lo - start;
    float denom = (float)(cnt > 0 ? cnt : 1);
    __shared__ float gS[64], yS[64];
    gS[c] = gsums[(size_t)g * 64 + c] / denom;
    __syncthreads();
    float y = bl1[c];
    for (int k = 0; k < 64; ++k) y += gS[k] * Wl1[k * 64 + c];
    yS[c] = fmaxf(y, 0.f);
    __syncthreads();
    if (c < 3) {
        float o = bl2[c];
        for (int k = 0; k < 64; ++k) o += yS[k] * Wl2[k * 3 + c];
        out[g * 3 + c] = o;
    }
}

extern "C" void kernel_launch(void* const* d_in, const int* in_sizes, int n_in,
                              void* d_out, int out_size, void* d_ws, size_t ws_size,
                              hipStream_t stream) {
    const float* x     = (const float*)d_in[0];
    const int*   eid   = (const int*)d_in[1];
    const float* attr  = (const float*)d_in[2];
    const int*   batch = (const int*)d_in[3];
    const float* Wemb  = (const float*)d_in[4];
    const float* bemb  = (const float*)d_in[5];
    const float* W1    = (const float*)d_in[6];
    const float* b1    = (const float*)d_in[7];
    const float* W2    = (const float*)d_in[8];
    const float* W3    = (const float*)d_in[9];
    const float* b3    = (const float*)d_in[10];
    const float* gamma = (const float*)d_in[11];
    const float* beta  = (const float*)d_in[12];
    const float* Wl1   = (const float*)d_in[13];
    const float* bl1   = (const float*)d_in[14];
    const float* Wl2   = (const float*)d_in[15];
    const float* bl2   = (const float*)d_in[16];

    int N = in_sizes[3];
    int E = in_sizes[2];
    int L = in_sizes[7] / 64;
    int G = out_size / 3;

    const int* src = eid;
    const int* dst = eid + E;

    float* ws      = (float*)d_ws;
    float* h       = ws;                       // N*64
    float* S       = h + (size_t)N * 64;       // N*64
    float* degw    = S + (size_t)N * 64;       // N
    float* bnstats = degw + N;                 // 3*128 (per-layer slots)
    float* gsums   = bnstats + 3 * 128;        // G*64
    int*   deg     = (int*)(gsums + (size_t)G * 64);  // N
    int*   rowptr  = deg + N;                  // N+2
    int*   bsum    = rowptr + (N + 2);         // 1024
    int*   gcur    = bsum + 1024;              // 1024 (bucket cursors)
    unsigned long long* edata = (unsigned long long*)(gcur + 1024);  // E
    unsigned long long* tmp   = edata + E;                           // E

    int nScanBlocks = (N + 1023) / 1024;
    int NB = (N + 255) >> 8;  // 256-node buckets (requires N < 2^24, NB <= 1024)

    // ---- CSR build + two-level counting sort of edges by dst ----
    hipMemsetAsync(deg, 0, (size_t)N * sizeof(int), stream);
    hipMemsetAsync(bnstats, 0, 3 * 128 * sizeof(float), stream);
    k_embed<<<(N * 64 + 255) / 256, 256, 0, stream>>>(x, Wemb, bemb, h, N);
    k_hist<<<(E + 255) / 256, 256, 0, stream>>>(dst, deg, E);
    k_blocksum<<<nScanBlocks, 256, 0, stream>>>(deg, bsum, N);
    k_scanpartials<<<1, 1024, 0, stream>>>(bsum, nScanBlocks);
    k_applyscan<<<nScanBlocks, 256, 0, stream>>>(deg, bsum, rowptr, gcur, N, E);
    k_binA<<<(E + ABLK - 1) / ABLK, 1024, 0, stream>>>(src, dst, attr, gcur, tmp, E, N);
    k_binB<<<NB, 256, 0, stream>>>(rowptr, tmp, edata, N);

    // ---- layers: split kernels, lazy BN, per-layer stats slots ----
    int gGrid = (N * 64 + 255) / 256;
    for (int l = 0; l < L; ++l) {
        int act = (l > 0) ? 1 : 0;
        const float* bsp  = bnstats + (size_t)(l > 0 ? l - 1 : 0) * 128;
        const float* gamp = gamma + (size_t)(l > 0 ? l - 1 : 0) * 64;
        const float* betp = beta + (size_t)(l > 0 ? l - 1 : 0) * 64;
        if (l == 0)
            k_gather<0, 1><<<gGrid, 256, 0, stream>>>(rowptr, edata, h, bsp, gamp, betp,
                                                      S, degw, N);
        else
            k_gather<1, 0><<<gGrid, 256, 0, stream>>>(rowptr, edata, h, bsp, gamp, betp,
                                                      S, degw, N);
        k_update<<<512, 512, 0, stream>>>(S, h, degw, bsp, gamp, betp, act,
                                          W1 + (size_t)l * 4096, b1 + (size_t)l * 64,
                                          W2 + (size_t)l * 4096, W3 + (size_t)l * 4096,
                                          b3 + (size_t)l * 64, bnstats + (size_t)l * 128, N);
    }

    // ---- pool (applies final BN affine + relu lazily) + head ----
    hipMemsetAsync(gsums, 0, (size_t)G * 64 * sizeof(float), stream);
    k_poolsum<<<(N + POOL_TILE - 1) / POOL_TILE, 256, 0, stream>>>(
        h, batch, bnstats + (size_t)(L - 1) * 128, gamma + (size_t)(L - 1) * 64,
        beta + (size_t)(L - 1) * 64, gsums, N);
    k_head<<<G, 64, 0, stream>>>(gsums, batch, Wl1, bl1, Wl2, bl2, (float*)d_out, N);
}

// Round 17
// 590.455 us; speedup vs baseline: 1.1087x; 1.0036x over previous
//
#include <hip/hip_runtime.h>

#define BN_EPS 1e-5f

// ---------------- embedding: h = x @ W_emb + b_emb  (x is [N,4]) ----------------
__global__ void k_embed(const float* __restrict__ x, const float* __restrict__ Wemb,
                        const float* __restrict__ bemb, float* __restrict__ h, int N) {
    int t = blockIdx.x * blockDim.x + threadIdx.x;
    int n = t >> 6, c = t & 63;
    if (n >= N) return;
    const float* xr = x + (size_t)n * 4;
    float acc = bemb[c];
    acc += xr[0] * Wemb[0 * 64 + c];
    acc += xr[1] * Wemb[1 * 64 + c];
    acc += xr[2] * Wemb[2 * 64 + c];
    acc += xr[3] * Wemb[3 * 64 + c];
    h[t] = acc;
}

// ---------------- CSR build: histogram of dst ----------------
__global__ void k_hist(const int* __restrict__ dst, int* __restrict__ deg, int E) {
    int e = blockIdx.x * blockDim.x + threadIdx.x;
    if (e < E) atomicAdd(&deg[dst[e]], 1);
}

// ---------------- scan phase 1: per-block sums (1024 elems / 256-thread block) --
__global__ __launch_bounds__(256) void k_blocksum(const int* __restrict__ deg,
                                                  int* __restrict__ bsum, int N) {
    __shared__ int red[256];
    int tid = threadIdx.x;
    int base = blockIdx.x * 1024 + tid * 4;
    int s = 0;
    if (base + 3 < N) {
        int4 v = *(const int4*)&deg[base];
        s = v.x + v.y + v.z + v.w;
    } else {
        for (int i = 0; i < 4; ++i) if (base + i < N) s += deg[base + i];
    }
    red[tid] = s;
    __syncthreads();
    for (int d = 128; d > 0; d >>= 1) {
        if (tid < d) red[tid] += red[tid + d];
        __syncthreads();
    }
    if (tid == 0) bsum[blockIdx.x] = red[0];
}

// ---------------- scan phase 2: exclusive scan of block sums (nb <= 1024) -------
__global__ __launch_bounds__(1024) void k_scanpartials(int* __restrict__ bsum, int nb) {
    __shared__ int t[1024];
    int tid = threadIdx.x;
    int v = (tid < nb) ? bsum[tid] : 0;
    t[tid] = v;
    __syncthreads();
    for (int d = 1; d < 1024; d <<= 1) {
        int u = (tid >= d) ? t[tid - d] : 0;
        __syncthreads();
        t[tid] += u;
        __syncthreads();
    }
    if (tid < nb) bsum[tid] = t[tid] - v;  // exclusive
}

// ---- scan phase 3: per-block scan + offset, write rowptr (+ bucket cursors) ----
__global__ __launch_bounds__(256) void k_applyscan(const int* __restrict__ deg,
                                                   const int* __restrict__ bsum,
                                                   int* __restrict__ rowptr,
                                                   int* __restrict__ gcur, int N, int E) {
    __shared__ int red[256];
    int tid = threadIdx.x;
    int base = blockIdx.x * 1024 + tid * 4;
    int v0 = 0, v1 = 0, v2 = 0, v3 = 0;
    if (base + 3 < N) {
        int4 v = *(const int4*)&deg[base];
        v0 = v.x; v1 = v.y; v2 = v.z; v3 = v.w;
    } else {
        if (base < N) v0 = deg[base];
        if (base + 1 < N) v1 = deg[base + 1];
        if (base + 2 < N) v2 = deg[base + 2];
        if (base + 3 < N) v3 = deg[base + 3];
    }
    int s = v0 + v1 + v2 + v3;
    red[tid] = s;
    __syncthreads();
    for (int d = 1; d < 256; d <<= 1) {
        int u = (tid >= d) ? red[tid - d] : 0;
        __syncthreads();
        red[tid] += u;
        __syncthreads();
    }
    int off = bsum[blockIdx.x] + red[tid] - s;
    int r0 = off, r1 = off + v0, r2 = r1 + v1, r3 = r2 + v2;
    if (base < N)     rowptr[base] = r0;
    if (base + 1 < N) rowptr[base + 1] = r1;
    if (base + 2 < N) rowptr[base + 2] = r2;
    if (base + 3 < N) rowptr[base + 3] = r3;
    if ((base & 255) == 0 && base < N) gcur[base >> 8] = r0;  // fused k_initbcur
    if (blockIdx.x == 0 && tid == 0) rowptr[N] = E;
}

// ------- sort pass A: partition edges into 256-node buckets (requires N < 2^24) -
#define ABLK 8192
__global__ __launch_bounds__(1024) void k_binA(const int* __restrict__ src,
                                               const int* __restrict__ dst,
                                               const float* __restrict__ attr,
                                               int* __restrict__ gcur,
                                               unsigned long long* __restrict__ tmp,
                                               int E, int N) {
    __shared__ int hist[1024];
    __shared__ int lcur[1024];
    int tid = threadIdx.x;
    int NB = (N + 255) >> 8;  // <= 1024 for N <= 262144
    int e0 = blockIdx.x * ABLK;
    int e1 = e0 + ABLK; if (e1 > E) e1 = E;
    for (int i = tid; i < NB; i += 1024) hist[i] = 0;
    __syncthreads();
    for (int e = e0 + tid; e < e1; e += 1024) atomicAdd(&hist[dst[e] >> 8], 1);
    __syncthreads();
    for (int b = tid; b < NB; b += 1024) {
        int hc = hist[b];
        lcur[b] = hc ? atomicAdd(&gcur[b], hc) : 0;
    }
    __syncthreads();
    for (int e = e0 + tid; e < e1; e += 1024) {
        int d = dst[e];
        int pos = atomicAdd(&lcur[d >> 8], 1);
        unsigned long long p = ((unsigned long long)__float_as_uint(attr[e]) << 32) |
                               ((unsigned long long)(d & 255) << 24) |
                               (unsigned int)src[e];
        tmp[pos] = p;
    }
}

// ------- sort pass B: one block per bucket; exact node placement via LDS cursors.
// Final edata word: [attr:32 | src*256:32] (byte offset of the h row).
__global__ __launch_bounds__(256) void k_binB(const int* __restrict__ rowptr,
                                              const unsigned long long* __restrict__ tmp,
                                              unsigned long long* __restrict__ edata,
                                              int N) {
    __shared__ int cur[256];
    int b = blockIdx.x;
    int tid = threadIdx.x;
    int nb0 = b << 8;
    int node = nb0 + tid;
    cur[tid] = (node < N) ? rowptr[node] : 0;
    int beg = rowptr[nb0];
    int endnode = nb0 + 256; if (endnode > N) endnode = N;
    int end = rowptr[endnode];
    __syncthreads();
    for (int e = beg + tid; e < end; e += 256) {
        unsigned long long p = tmp[e];
        int dl = (int)((p >> 24) & 255);
        int pos = atomicAdd(&cur[dl], 1);
        edata[pos] = (p & 0xFFFFFFFF00000000ull) | ((p & 0xFFFFFFull) << 8);
    }
}

// ---- inline BN scale/shift from raw stats (replaces the k_bnfinish kernel) ----
__device__ __forceinline__ void bn_coeff(const float* bs, const float* gam,
                                         const float* bet, int c, float inv_n,
                                         float& sc, float& sh) {
    float mean = bs[c] * inv_n;
    float var = bs[64 + c] * inv_n - mean * mean;
    sc = gam[c] * rsqrtf(fmaxf(var, 0.f) + BN_EPS);
    sh = bet[c] - mean * sc;
}

// ------- pull gather with lazy BN: S[n] = sum_e w_e * act(h_raw[src_e]) --------
template <int ACT, int SAVEDW>
__global__ void k_gather(const int* __restrict__ rowptr,
                         const unsigned long long* __restrict__ edata,
                         const float* __restrict__ h,
                         const float* __restrict__ bsp, const float* __restrict__ gamp,
                         const float* __restrict__ betp,
                         float* __restrict__ S, float* __restrict__ degw, int N) {
    int t = blockIdx.x * blockDim.x + threadIdx.x;
    int n = t >> 6, c = t & 63;
    if (n >= N) return;
    unsigned c4 = (unsigned)(c << 2);
    float sc = 1.f, sh = 0.f;
    if (ACT) bn_coeff(bsp, gamp, betp, c, 1.f / (float)N, sc, sh);
    int beg = rowptr[n], end = rowptr[n + 1];
    int len = end - beg;
    float acc[8] = {0.f, 0.f, 0.f, 0.f, 0.f, 0.f, 0.f, 0.f};
    float wsum = 0.f;
    int nFull = len & ~7;
    for (int base = 0; base < nFull; base += 8) {
#pragma unroll
        for (int i = 0; i < 8; ++i) {
            unsigned long long p = edata[beg + base + i];
            float w = __uint_as_float((unsigned)(p >> 32));
            unsigned off = (unsigned)p;  // src*256
            float v = *(const float*)((const char*)h + (off | c4));
            if (ACT) v = fmaxf(fmaf(v, sc, sh), 0.f);
            acc[i] += w * v;
            if (SAVEDW) wsum += w;
        }
    }
    if (nFull < len) {
#pragma unroll
        for (int i = 0; i < 8; ++i) {
            int idx = nFull + i;
            int ce = beg + (idx < len ? idx : len - 1);
            unsigned long long p = edata[ce];
            float w = (idx < len) ? __uint_as_float((unsigned)(p >> 32)) : 0.f;
            unsigned off = (unsigned)p;
            float v = *(const float*)((const char*)h + (off | c4));
            if (ACT) v = fmaxf(fmaf(v, sc, sh), 0.f);
            acc[i] += w * v;
            if (SAVEDW) wsum += w;
        }
    }
    float r = ((acc[0] + acc[1]) + (acc[2] + acc[3])) +
              ((acc[4] + acc[5]) + (acc[6] + acc[7]));
    S[(size_t)n * 64 + c] = r;
    if (SAVEDW && c == 0) degw[n] = wsum;
}

// --- h_raw_out = S@W1 + x@W3 - dw*(x@W2) + dw*b1 + b3 (in place, x=act(h_raw));
// Proven [k][c] weight layout + per-lane b32 weight reads. Row values read as
// wave-uniform b128 broadcasts (k unrolled by 4): LDS ops per 4-k group drop
// 44 -> 20 (12 weight b32 + 8 row b128) vs 48 FMAs. (R14's conflicts came from
// the transposed-weight staging, not broadcasts; weight layout unchanged here.)
__global__ __launch_bounds__(512) void k_update(
    const float* __restrict__ S, float* __restrict__ h,
    const float* __restrict__ degw,
    const float* __restrict__ bsp, const float* __restrict__ gamp,
    const float* __restrict__ betp, int act,
    const float* __restrict__ W1, const float* __restrict__ b1,
    const float* __restrict__ W2, const float* __restrict__ W3,
    const float* __restrict__ b3,
    float* __restrict__ bnstats, int N) {
    __shared__ float W1s[64 * 64], W2s[64 * 64], W3s[64 * 64];
    __shared__ float sS[32 * 64], sh[32 * 64];
    __shared__ float dwS[32];
    int tid = threadIdx.x;
    for (int i = tid * 4; i < 4096; i += 2048) {
        *(float4*)&W1s[i] = *(const float4*)&W1[i];
        *(float4*)&W2s[i] = *(const float4*)&W2[i];
        *(float4*)&W3s[i] = *(const float4*)&W3[i];
    }
    int c = tid & 63, w = tid >> 6;  // 8 waves; wave w handles rows w+8m, m=0..3
    float b1c = b1[c], b3c = b3[c];
    float bsum = 0.f, bsq = 0.f;
    int lc = (tid * 4) & 63;
    float4 sc4 = {1.f, 1.f, 1.f, 1.f}, sh4 = {0.f, 0.f, 0.f, 0.f};
    if (act) {
        float inv_n = 1.f / (float)N;
        bn_coeff(bsp, gamp, betp, lc + 0, inv_n, sc4.x, sh4.x);
        bn_coeff(bsp, gamp, betp, lc + 1, inv_n, sc4.y, sh4.y);
        bn_coeff(bsp, gamp, betp, lc + 2, inv_n, sc4.z, sh4.z);
        bn_coeff(bsp, gamp, betp, lc + 3, inv_n, sc4.w, sh4.w);
    }
    int numTiles = (N + 31) / 32;
    for (int tile = blockIdx.x; tile < numTiles; tile += gridDim.x) {
        int n0 = tile * 32;
        __syncthreads();
        {
            int idx = tid * 4;
            int nrow = idx >> 6;
            if (n0 + nrow < N) {
                int base = n0 * 64;
                *(float4*)&sS[idx] = *(const float4*)&S[base + idx];
                float4 v = *(const float4*)&h[base + idx];
                if (act) {
                    v.x = fmaxf(fmaf(v.x, sc4.x, sh4.x), 0.f);
                    v.y = fmaxf(fmaf(v.y, sc4.y, sh4.y), 0.f);
                    v.z = fmaxf(fmaf(v.z, sc4.z, sh4.z), 0.f);
                    v.w = fmaxf(fmaf(v.w, sc4.w, sh4.w), 0.f);
                }
                *(float4*)&sh[idx] = v;
            } else {
                sS[idx] = sS[idx + 1] = sS[idx + 2] = sS[idx + 3] = 0.f;
                sh[idx] = sh[idx + 1] = sh[idx + 2] = sh[idx + 3] = 0.f;
            }
            if (tid < 32) dwS[tid] = (n0 + tid < N) ? degw[n0 + tid] : 0.f;
        }
        __syncthreads();
        float aA[4] = {0, 0, 0, 0}, aB[4] = {0, 0, 0, 0}, aC[4] = {0, 0, 0, 0};
        for (int k = 0; k < 64; k += 4) {
            float w1a[4], w2a[4], w3a[4];
#pragma unroll
            for (int j = 0; j < 4; ++j) {
                w1a[j] = W1s[(k + j) * 64 + c];
                w2a[j] = W2s[(k + j) * 64 + c];
                w3a[j] = W3s[(k + j) * 64 + c];
            }
#pragma unroll
            for (int m = 0; m < 4; ++m) {
                int nl = w + 8 * m;
                float4 sv = *(const float4*)&sS[nl * 64 + k];  // b128 broadcast
                float4 hv = *(const float4*)&sh[nl * 64 + k];
                aA[m] = fmaf(sv.w, w1a[3], fmaf(sv.z, w1a[2],
                         fmaf(sv.y, w1a[1], fmaf(sv.x, w1a[0], aA[m]))));
                aB[m] = fmaf(hv.w, w2a[3], fmaf(hv.z, w2a[2],
                         fmaf(hv.y, w2a[1], fmaf(hv.x, w2a[0], aB[m]))));
                aC[m] = fmaf(hv.w, w3a[3], fmaf(hv.z, w3a[2],
                         fmaf(hv.y, w3a[1], fmaf(hv.x, w3a[0], aC[m]))));
            }
        }
#pragma unroll
        for (int m = 0; m < 4; ++m) {
            int nl = w + 8 * m;
            int n = n0 + nl;
            if (n < N) {
                float dw = dwS[nl];
                float val = aA[m] + aC[m] - dw * aB[m] + dw * b1c + b3c;
                h[(size_t)n * 64 + c] = val;  // raw (pre-BN); tile already staged
                bsum += val;
                bsq += val * val;
            }
        }
    }
    // ---- BN stats reduction (reuse sS: needs 1024 floats) ----
    __syncthreads();
    sS[tid] = bsum;
    sS[512 + tid] = bsq;
    __syncthreads();
    if (tid < 64) {
        float s = 0.f, q = 0.f;
#pragma unroll
        for (int i = 0; i < 8; ++i) {
            s += sS[tid + i * 64];
            q += sS[512 + tid + i * 64];
        }
        atomicAdd(&bnstats[tid], s);
        atomicAdd(&bnstats[64 + tid], q);
    }
}

// ------- pool phase 1: per-graph sums of act(h_raw), sorted-run + atomics -------
#define POOL_TILE 128
__global__ __launch_bounds__(256) void k_poolsum(const float* __restrict__ h,
                                                 const int* __restrict__ batch,
                                                 const float* __restrict__ bsp,
                                                 const float* __restrict__ gamp,
                                                 const float* __restrict__ betp,
                                                 float* __restrict__ gsums, int N) {
    int tid = threadIdx.x;
    int c = tid & 63, q = tid >> 6;
    float sc, sh_;
    bn_coeff(bsp, gamp, betp, c, 1.f / (float)N, sc, sh_);
    int n0 = blockIdx.x * POOL_TILE;
    int nEnd = n0 + POOL_TILE; if (nEnd > N) nEnd = N;
    int g = -1;
    float acc = 0.f;
    for (int n = n0 + q; n < nEnd; n += 4) {
        int b = batch[n];
        if (b != g) {
            if (g >= 0) atomicAdd(&gsums[(size_t)g * 64 + c], acc);
            g = b; acc = 0.f;
        }
        acc += fmaxf(fmaf(h[(size_t)n * 64 + c], sc, sh_), 0.f);
    }
    if (g >= 0) atomicAdd(&gsums[(size_t)g * 64 + c], acc);
}

// ------- pool phase 2: divide by count + MLP head (one 64-thread block / graph) -
__global__ void k_head(const float* __restrict__ gsums, const int* __restrict__ batch,
                       const float* __restrict__ Wl1, const float* __restrict__ bl1,
                       const float* __restrict__ Wl2, const float* __restrict__ bl2,
                       float* __restrict__ out, int N) {
    int g = blockIdx.x;
    int c = threadIdx.x;  // 64 threads
    int lo = 0, hi = N;
    while (lo < hi) { int mid = (lo + hi) >> 1; if (batch[mid] < g) lo = mid + 1; else hi = mid; }
    int start = lo;
    hi = N;
    while (lo < hi) { int mid = (lo + hi) >> 1; if (batch[mid] < g + 1) lo = mid + 1; else hi = mid; }
    int cnt = lo - start;
    float denom = (float)(cnt > 0 ? cnt : 1);
    __shared__ float gS[64], yS[64];
    gS[c] = gsums[(size_t)g * 64 + c] / denom;
    __syncthreads();
    float y = bl1[c];
    for (int k = 0; k < 64; ++k) y += gS[k] * Wl1[k * 64 + c];
    yS[c] = fmaxf(y, 0.f);
    __syncthreads();
    if (c < 3) {
        float o = bl2[c];
        for (int k = 0; k < 64; ++k) o += yS[k] * Wl2[k * 3 + c];
        out[g * 3 + c] = o;
    }
}

extern "C" void kernel_launch(void* const* d_in, const int* in_sizes, int n_in,
                              void* d_out, int out_size, void* d_ws, size_t ws_size,
                              hipStream_t stream) {
    const float* x     = (const float*)d_in[0];
    const int*   eid   = (const int*)d_in[1];
    const float* attr  = (const float*)d_in[2];
    const int*   batch = (const int*)d_in[3];
    const float* Wemb  = (const float*)d_in[4];
    const float* bemb  = (const float*)d_in[5];
    const float* W1    = (const float*)d_in[6];
    const float* b1    = (const float*)d_in[7];
    const float* W2    = (const float*)d_in[8];
    const float* W3    = (const float*)d_in[9];
    const float* b3    = (const float*)d_in[10];
    const float* gamma = (const float*)d_in[11];
    const float* beta  = (const float*)d_in[12];
    const float* Wl1   = (const float*)d_in[13];
    const float* bl1   = (const float*)d_in[14];
    const float* Wl2   = (const float*)d_in[15];
    const float* bl2   = (const float*)d_in[16];

    int N = in_sizes[3];
    int E = in_sizes[2];
    int L = in_sizes[7] / 64;
    int G = out_size / 3;

    const int* src = eid;
    const int* dst = eid + E;

    float* ws      = (float*)d_ws;
    float* h       = ws;                       // N*64
    float* S       = h + (size_t)N * 64;       // N*64
    float* degw    = S + (size_t)N * 64;       // N
    float* bnstats = degw + N;                 // 3*128 (per-layer slots)
    float* gsums   = bnstats + 3 * 128;        // G*64
    int*   deg     = (int*)(gsums + (size_t)G * 64);  // N
    int*   rowptr  = deg + N;                  // N+2
    int*   bsum    = rowptr + (N + 2);         // 1024
    int*   gcur    = bsum + 1024;              // 1024 (bucket cursors)
    unsigned long long* edata = (unsigned long long*)(gcur + 1024);  // E
    unsigned long long* tmp   = edata + E;                           // E

    int nScanBlocks = (N + 1023) / 1024;
    int NB = (N + 255) >> 8;  // 256-node buckets (requires N < 2^24, NB <= 1024)

    // ---- CSR build + two-level counting sort of edges by dst ----
    hipMemsetAsync(deg, 0, (size_t)N * sizeof(int), stream);
    hipMemsetAsync(bnstats, 0, 3 * 128 * sizeof(float), stream);
    k_embed<<<(N * 64 + 255) / 256, 256, 0, stream>>>(x, Wemb, bemb, h, N);
    k_hist<<<(E + 255) / 256, 256, 0, stream>>>(dst, deg, E);
    k_blocksum<<<nScanBlocks, 256, 0, stream>>>(deg, bsum, N);
    k_scanpartials<<<1, 1024, 0, stream>>>(bsum, nScanBlocks);
    k_applyscan<<<nScanBlocks, 256, 0, stream>>>(deg, bsum, rowptr, gcur, N, E);
    k_binA<<<(E + ABLK - 1) / ABLK, 1024, 0, stream>>>(src, dst, attr, gcur, tmp, E, N);
    k_binB<<<NB, 256, 0, stream>>>(rowptr, tmp, edata, N);

    // ---- layers: split kernels, lazy BN, per-layer stats slots ----
    int gGrid = (N * 64 + 255) / 256;
    for (int l = 0; l < L; ++l) {
        int act = (l > 0) ? 1 : 0;
        const float* bsp  = bnstats + (size_t)(l > 0 ? l - 1 : 0) * 128;
        const float* gamp = gamma + (size_t)(l > 0 ? l - 1 : 0) * 64;
        const float* betp = beta + (size_t)(l > 0 ? l - 1 : 0) * 64;
        if (l == 0)
            k_gather<0, 1><<<gGrid, 256, 0, stream>>>(rowptr, edata, h, bsp, gamp, betp,
                                                      S, degw, N);
        else
            k_gather<1, 0><<<gGrid, 256, 0, stream>>>(rowptr, edata, h, bsp, gamp, betp,
                                                      S, degw, N);
        k_update<<<512, 512, 0, stream>>>(S, h, degw, bsp, gamp, betp, act,
                                          W1 + (size_t)l * 4096, b1 + (size_t)l * 64,
                                          W2 + (size_t)l * 4096, W3 + (size_t)l * 4096,
                                          b3 + (size_t)l * 64, bnstats + (size_t)l * 128, N);
    }

    // ---- pool (applies final BN affine + relu lazily) + head ----
    hipMemsetAsync(gsums, 0, (size_t)G * 64 * sizeof(float), stream);
    k_poolsum<<<(N + POOL_TILE - 1) / POOL_TILE, 256, 0, stream>>>(
        h, batch, bnstats + (size_t)(L - 1) * 128, gamma + (size_t)(L - 1) * 64,
        beta + (size_t)(L - 1) * 64, gsums, N);
    k_head<<<G, 64, 0, stream>>>(gsums, batch, Wl1, bl1, Wl2, bl2, (float*)d_out, N);
}

// Round 19
// 529.080 us; speedup vs baseline: 1.2373x; 1.1160x over previous
//
#include <hip/hip_runtime.h>

#define BN_EPS 1e-5f

// ---------------- CSR build: histogram of dst ----------------
__global__ void k_hist(const int* __restrict__ dst, int* __restrict__ deg, int E) {
    int e = blockIdx.x * blockDim.x + threadIdx.x;
    if (e < E) atomicAdd(&deg[dst[e]], 1);
}

// ---------------- scan phase 1: per-block sums (1024 elems / 256-thread block) --
__global__ __launch_bounds__(256) void k_blocksum(const int* __restrict__ deg,
                                                  int* __restrict__ bsum, int N) {
    __shared__ int red[256];
    int tid = threadIdx.x;
    int base = blockIdx.x * 1024 + tid * 4;
    int s = 0;
    if (base + 3 < N) {
        int4 v = *(const int4*)&deg[base];
        s = v.x + v.y + v.z + v.w;
    } else {
        for (int i = 0; i < 4; ++i) if (base + i < N) s += deg[base + i];
    }
    red[tid] = s;
    __syncthreads();
    for (int d = 128; d > 0; d >>= 1) {
        if (tid < d) red[tid] += red[tid + d];
        __syncthreads();
    }
    if (tid == 0) bsum[blockIdx.x] = red[0];
}

// ---------------- scan phase 2: exclusive scan of block sums (nb <= 1024) -------
__global__ __launch_bounds__(1024) void k_scanpartials(int* __restrict__ bsum, int nb) {
    __shared__ int t[1024];
    int tid = threadIdx.x;
    int v = (tid < nb) ? bsum[tid] : 0;
    t[tid] = v;
    __syncthreads();
    for (int d = 1; d < 1024; d <<= 1) {
        int u = (tid >= d) ? t[tid - d] : 0;
        __syncthreads();
        t[tid] += u;
        __syncthreads();
    }
    if (tid < nb) bsum[tid] = t[tid] - v;  // exclusive
}

// ---- scan phase 3: per-block scan + offset, write rowptr (+ bucket cursors) ----
__global__ __launch_bounds__(256) void k_applyscan(const int* __restrict__ deg,
                                                   const int* __restrict__ bsum,
                                                   int* __restrict__ rowptr,
                                                   int* __restrict__ gcur, int N, int E) {
    __shared__ int red[256];
    int tid = threadIdx.x;
    int base = blockIdx.x * 1024 + tid * 4;
    int v0 = 0, v1 = 0, v2 = 0, v3 = 0;
    if (base + 3 < N) {
        int4 v = *(const int4*)&deg[base];
        v0 = v.x; v1 = v.y; v2 = v.z; v3 = v.w;
    } else {
        if (base < N) v0 = deg[base];
        if (base + 1 < N) v1 = deg[base + 1];
        if (base + 2 < N) v2 = deg[base + 2];
        if (base + 3 < N) v3 = deg[base + 3];
    }
    int s = v0 + v1 + v2 + v3;
    red[tid] = s;
    __syncthreads();
    for (int d = 1; d < 256; d <<= 1) {
        int u = (tid >= d) ? red[tid - d] : 0;
        __syncthreads();
        red[tid] += u;
        __syncthreads();
    }
    int off = bsum[blockIdx.x] + red[tid] - s;
    int r0 = off, r1 = off + v0, r2 = r1 + v1, r3 = r2 + v2;
    if (base < N)     rowptr[base] = r0;
    if (base + 1 < N) rowptr[base + 1] = r1;
    if (base + 2 < N) rowptr[base + 2] = r2;
    if (base + 3 < N) rowptr[base + 3] = r3;
    if ((base & 255) == 0 && base < N) gcur[base >> 8] = r0;  // fused k_initbcur
    if (blockIdx.x == 0 && tid == 0) rowptr[N] = E;
}

// ------- sort pass A: partition edges into 256-node buckets (requires N < 2^24) -
#define ABLK 8192
__global__ __launch_bounds__(1024) void k_binA(const int* __restrict__ src,
                                               const int* __restrict__ dst,
                                               const float* __restrict__ attr,
                                               int* __restrict__ gcur,
                                               unsigned long long* __restrict__ tmp,
                                               int E, int N) {
    __shared__ int hist[1024];
    __shared__ int lcur[1024];
    int tid = threadIdx.x;
    int NB = (N + 255) >> 8;  // <= 1024 for N <= 262144
    int e0 = blockIdx.x * ABLK;
    int e1 = e0 + ABLK; if (e1 > E) e1 = E;
    for (int i = tid; i < NB; i += 1024) hist[i] = 0;
    __syncthreads();
    for (int e = e0 + tid; e < e1; e += 1024) atomicAdd(&hist[dst[e] >> 8], 1);
    __syncthreads();
    for (int b = tid; b < NB; b += 1024) {
        int hc = hist[b];
        lcur[b] = hc ? atomicAdd(&gcur[b], hc) : 0;
    }
    __syncthreads();
    for (int e = e0 + tid; e < e1; e += 1024) {
        int d = dst[e];
        int pos = atomicAdd(&lcur[d >> 8], 1);
        unsigned long long p = ((unsigned long long)__float_as_uint(attr[e]) << 32) |
                               ((unsigned long long)(d & 255) << 24) |
                               (unsigned int)src[e];
        tmp[pos] = p;
    }
}

// ------- sort pass B: one block per bucket; exact node placement via LDS cursors.
// Final edata word: [attr:32 | src*256:32] (byte offset of the 64ch h row).
__global__ __launch_bounds__(256) void k_binB(const int* __restrict__ rowptr,
                                              const unsigned long long* __restrict__ tmp,
                                              unsigned long long* __restrict__ edata,
                                              int N) {
    __shared__ int cur[256];
    int b = blockIdx.x;
    int tid = threadIdx.x;
    int nb0 = b << 8;
    int node = nb0 + tid;
    cur[tid] = (node < N) ? rowptr[node] : 0;
    int beg = rowptr[nb0];
    int endnode = nb0 + 256; if (endnode > N) endnode = N;
    int end = rowptr[endnode];
    __syncthreads();
    for (int e = beg + tid; e < end; e += 256) {
        unsigned long long p = tmp[e];
        int dl = (int)((p >> 24) & 255);
        int pos = atomicAdd(&cur[dl], 1);
        edata[pos] = (p & 0xFFFFFFFF00000000ull) | ((p & 0xFFFFFFull) << 8);
    }
}

// ---- inline BN scale/shift from raw stats ----
__device__ __forceinline__ void bn_coeff(const float* bs, const float* gam,
                                         const float* bet, int c, float inv_n,
                                         float& sc, float& sh) {
    float mean = bs[c] * inv_n;
    float var = bs[64 + c] * inv_n - mean * mean;
    sc = gam[c] * rsqrtf(fmaxf(var, 0.f) + BN_EPS);
    sh = bet[c] - mean * sc;
}

// ---- layer-0 gather on raw x (N x 4): g4[n] = sum_e w_e * x4[src_e]; degw ----
// x is 1.6MB (L2-resident); 16B/edge instead of 256B -> layer-0 gather is ~4x+
// cheaper than the 64ch version. S0 = g4@Wemb + degw*bemb folded into k_update.
__global__ void k_gather4(const int* __restrict__ rowptr,
                          const unsigned long long* __restrict__ edata,
                          const float* __restrict__ x,
                          float* __restrict__ g4, float* __restrict__ degw, int N) {
    int n = blockIdx.x * blockDim.x + threadIdx.x;
    if (n >= N) return;
    int beg = rowptr[n], end = rowptr[n + 1];
    float4 a0 = {0.f, 0.f, 0.f, 0.f}, a1 = {0.f, 0.f, 0.f, 0.f};
    float wsum = 0.f;
    int e = beg;
    for (; e + 1 < end; e += 2) {
        unsigned long long p0 = edata[e], p1 = edata[e + 1];
        float w0 = __uint_as_float((unsigned)(p0 >> 32));
        float w1 = __uint_as_float((unsigned)(p1 >> 32));
        float4 v0 = *(const float4*)((const char*)x + (((unsigned)p0) >> 4));
        float4 v1 = *(const float4*)((const char*)x + (((unsigned)p1) >> 4));
        a0.x += w0 * v0.x; a0.y += w0 * v0.y; a0.z += w0 * v0.z; a0.w += w0 * v0.w;
        a1.x += w1 * v1.x; a1.y += w1 * v1.y; a1.z += w1 * v1.z; a1.w += w1 * v1.w;
        wsum += w0 + w1;
    }
    if (e < end) {
        unsigned long long p0 = edata[e];
        float w0 = __uint_as_float((unsigned)(p0 >> 32));
        float4 v0 = *(const float4*)((const char*)x + (((unsigned)p0) >> 4));
        a0.x += w0 * v0.x; a0.y += w0 * v0.y; a0.z += w0 * v0.z; a0.w += w0 * v0.w;
        wsum += w0;
    }
    float4 r;
    r.x = a0.x + a1.x; r.y = a0.y + a1.y; r.z = a0.z + a1.z; r.w = a0.w + a1.w;
    *(float4*)&g4[(size_t)n * 4] = r;
    degw[n] = wsum;
}

// ------- pull gather with lazy BN: S[n] = sum_e w_e * act(h_raw[src_e]) --------
template <int ACT, int SAVEDW>
__global__ void k_gather(const int* __restrict__ rowptr,
                         const unsigned long long* __restrict__ edata,
                         const float* __restrict__ h,
                         const float* __restrict__ bsp, const float* __restrict__ gamp,
                         const float* __restrict__ betp,
                         float* __restrict__ S, float* __restrict__ degw, int N) {
    int t = blockIdx.x * blockDim.x + threadIdx.x;
    int n = t >> 6, c = t & 63;
    if (n >= N) return;
    unsigned c4 = (unsigned)(c << 2);
    float sc = 1.f, sh = 0.f;
    if (ACT) bn_coeff(bsp, gamp, betp, c, 1.f / (float)N, sc, sh);
    int beg = rowptr[n], end = rowptr[n + 1];
    int len = end - beg;
    float acc[8] = {0.f, 0.f, 0.f, 0.f, 0.f, 0.f, 0.f, 0.f};
    float wsum = 0.f;
    int nFull = len & ~7;
    for (int base = 0; base < nFull; base += 8) {
#pragma unroll
        for (int i = 0; i < 8; ++i) {
            unsigned long long p = edata[beg + base + i];
            float w = __uint_as_float((unsigned)(p >> 32));
            unsigned off = (unsigned)p;  // src*256
            float v = *(const float*)((const char*)h + (off | c4));
            if (ACT) v = fmaxf(fmaf(v, sc, sh), 0.f);
            acc[i] += w * v;
            if (SAVEDW) wsum += w;
        }
    }
    if (nFull < len) {
#pragma unroll
        for (int i = 0; i < 8; ++i) {
            int idx = nFull + i;
            int ce = beg + (idx < len ? idx : len - 1);
            unsigned long long p = edata[ce];
            float w = (idx < len) ? __uint_as_float((unsigned)(p >> 32)) : 0.f;
            unsigned off = (unsigned)p;
            float v = *(const float*)((const char*)h + (off | c4));
            if (ACT) v = fmaxf(fmaf(v, sc, sh), 0.f);
            acc[i] += w * v;
            if (SAVEDW) wsum += w;
        }
    }
    float r = ((acc[0] + acc[1]) + (acc[2] + acc[3])) +
              ((acc[4] + acc[5]) + (acc[6] + acc[7]));
    S[(size_t)n * 64 + c] = r;
    if (SAVEDW && c == 0) degw[n] = wsum;
}

// --- h_raw_out = S@W1 + x@W3 - dw*(x@W2) + dw*b1 + b3 (in place, x=act(h_raw));
// Proven R17 structure: [k][c] LDS weights, per-lane b32 weight reads, b128
// wave-uniform row broadcasts (k unrolled x4). EMB=1 (layer 0): S and x tiles
// reconstructed in staging from g4/x via the tiny 4x64 Wemb (S0 = g4@Wemb +
// dw*bemb; x0 = x@Wemb + bemb) -- no 64ch gather or k_embed needed at layer 0.
// bf16 MFMA variant failed accuracy (absmax 0.58 vs 9.5e-3) -- fp32 only.
template <int ACT, int EMB>
__global__ __launch_bounds__(512) void k_update(
    const float* __restrict__ S, float* __restrict__ h,
    const float* __restrict__ degw,
    const float* __restrict__ xin, const float* __restrict__ g4,
    const float* __restrict__ Wemb, const float* __restrict__ bemb,
    const float* __restrict__ bsp, const float* __restrict__ gamp,
    const float* __restrict__ betp,
    const float* __restrict__ W1, const float* __restrict__ b1,
    const float* __restrict__ W2, const float* __restrict__ W3,
    const float* __restrict__ b3,
    float* __restrict__ bnstats, int N) {
    __shared__ float W1s[64 * 64], W2s[64 * 64], W3s[64 * 64];
    __shared__ float sS[32 * 64], sh[32 * 64];
    __shared__ float dwS[32];
    int tid = threadIdx.x;
    for (int i = tid * 4; i < 4096; i += 2048) {
        *(float4*)&W1s[i] = *(const float4*)&W1[i];
        *(float4*)&W2s[i] = *(const float4*)&W2[i];
        *(float4*)&W3s[i] = *(const float4*)&W3[i];
    }
    int c = tid & 63, w = tid >> 6;  // 8 waves; wave w handles rows w+8m, m=0..3
    float b1c = b1[c], b3c = b3[c];
    float bsum = 0.f, bsq = 0.f;
    int lc = (tid * 4) & 63;
    float4 sc4 = {1.f, 1.f, 1.f, 1.f}, sh4 = {0.f, 0.f, 0.f, 0.f};
    if (ACT) {
        float inv_n = 1.f / (float)N;
        bn_coeff(bsp, gamp, betp, lc + 0, inv_n, sc4.x, sh4.x);
        bn_coeff(bsp, gamp, betp, lc + 1, inv_n, sc4.y, sh4.y);
        bn_coeff(bsp, gamp, betp, lc + 2, inv_n, sc4.z, sh4.z);
        bn_coeff(bsp, gamp, betp, lc + 3, inv_n, sc4.w, sh4.w);
    }
    // EMB: per-thread Wemb columns lc..lc+3 (tiny, L1-resident)
    float4 we0, we1, we2, we3, beV;
    if (EMB) {
        we0 = *(const float4*)&Wemb[0 * 64 + lc];
        we1 = *(const float4*)&Wemb[1 * 64 + lc];
        we2 = *(const float4*)&Wemb[2 * 64 + lc];
        we3 = *(const float4*)&Wemb[3 * 64 + lc];
        beV = *(const float4*)&bemb[lc];
    }
    int numTiles = (N + 31) / 32;
    for (int tile = blockIdx.x; tile < numTiles; tile += gridDim.x) {
        int n0 = tile * 32;
        __syncthreads();
        {
            int idx = tid * 4;
            int nrow = idx >> 6;
            int n = n0 + nrow;
            if (n < N) {
                if (EMB) {
                    float4 g = *(const float4*)&g4[(size_t)n * 4];
                    float4 xr = *(const float4*)&xin[(size_t)n * 4];
                    float dw = degw[n];
                    float4 sv, xv;
                    sv.x = g.x * we0.x + g.y * we1.x + g.z * we2.x + g.w * we3.x + dw * beV.x;
                    sv.y = g.x * we0.y + g.y * we1.y + g.z * we2.y + g.w * we3.y + dw * beV.y;
                    sv.z = g.x * we0.z + g.y * we1.z + g.z * we2.z + g.w * we3.z + dw * beV.z;
                    sv.w = g.x * we0.w + g.y * we1.w + g.z * we2.w + g.w * we3.w + dw * beV.w;
                    xv.x = xr.x * we0.x + xr.y * we1.x + xr.z * we2.x + xr.w * we3.x + beV.x;
                    xv.y = xr.x * we0.y + xr.y * we1.y + xr.z * we2.y + xr.w * we3.y + beV.y;
                    xv.z = xr.x * we0.z + xr.y * we1.z + xr.z * we2.z + xr.w * we3.z + beV.z;
                    xv.w = xr.x * we0.w + xr.y * we1.w + xr.z * we2.w + xr.w * we3.w + beV.w;
                    *(float4*)&sS[idx] = sv;
                    *(float4*)&sh[idx] = xv;
                } else {
                    int base = n0 * 64;
                    *(float4*)&sS[idx] = *(const float4*)&S[base + idx];
                    float4 v = *(const float4*)&h[base + idx];
                    if (ACT) {
                        v.x = fmaxf(fmaf(v.x, sc4.x, sh4.x), 0.f);
                        v.y = fmaxf(fmaf(v.y, sc4.y, sh4.y), 0.f);
                        v.z = fmaxf(fmaf(v.z, sc4.z, sh4.z), 0.f);
                        v.w = fmaxf(fmaf(v.w, sc4.w, sh4.w), 0.f);
                    }
                    *(float4*)&sh[idx] = v;
                }
            } else {
                sS[idx] = sS[idx + 1] = sS[idx + 2] = sS[idx + 3] = 0.f;
                sh[idx] = sh[idx + 1] = sh[idx + 2] = sh[idx + 3] = 0.f;
            }
            if (tid < 32) dwS[tid] = (n0 + tid < N) ? degw[n0 + tid] : 0.f;
        }
        __syncthreads();
        float aA[4] = {0, 0, 0, 0}, aB[4] = {0, 0, 0, 0}, aC[4] = {0, 0, 0, 0};
        for (int k = 0; k < 64; k += 4) {
            float w1a[4], w2a[4], w3a[4];
#pragma unroll
            for (int j = 0; j < 4; ++j) {
                w1a[j] = W1s[(k + j) * 64 + c];
                w2a[j] = W2s[(k + j) * 64 + c];
                w3a[j] = W3s[(k + j) * 64 + c];
            }
#pragma unroll
            for (int m = 0; m < 4; ++m) {
                int nl = w + 8 * m;
                float4 sv = *(const float4*)&sS[nl * 64 + k];  // b128 broadcast
                float4 hv = *(const float4*)&sh[nl * 64 + k];
                aA[m] = fmaf(sv.w, w1a[3], fmaf(sv.z, w1a[2],
                         fmaf(sv.y, w1a[1], fmaf(sv.x, w1a[0], aA[m]))));
                aB[m] = fmaf(hv.w, w2a[3], fmaf(hv.z, w2a[2],
                         fmaf(hv.y, w2a[1], fmaf(hv.x, w2a[0], aB[m]))));
                aC[m] = fmaf(hv.w, w3a[3], fmaf(hv.z, w3a[2],
                         fmaf(hv.y, w3a[1], fmaf(hv.x, w3a[0], aC[m]))));
            }
        }
#pragma unroll
        for (int m = 0; m < 4; ++m) {
            int nl = w + 8 * m;
            int n = n0 + nl;
            if (n < N) {
                float dw = dwS[nl];
                float val = aA[m] + aC[m] - dw * aB[m] + dw * b1c + b3c;
                h[(size_t)n * 64 + c] = val;  // raw (pre-BN)
                bsum += val;
                bsq += val * val;
            }
        }
    }
    // ---- BN stats reduction (reuse sS: needs 1024 floats) ----
    __syncthreads();
    sS[tid] = bsum;
    sS[512 + tid] = bsq;
    __syncthreads();
    if (tid < 64) {
        float s = 0.f, q = 0.f;
#pragma unroll
        for (int i = 0; i < 8; ++i) {
            s += sS[tid + i * 64];
            q += sS[512 + tid + i * 64];
        }
        atomicAdd(&bnstats[tid], s);
        atomicAdd(&bnstats[64 + tid], q);
    }
}

// ------- pool phase 1: per-graph sums of act(h_raw), sorted-run + atomics -------
#define POOL_TILE 128
__global__ __launch_bounds__(256) void k_poolsum(const float* __restrict__ h,
                                                 const int* __restrict__ batch,
                                                 const float* __restrict__ bsp,
                                                 const float* __restrict__ gamp,
                                                 const float* __restrict__ betp,
                                                 float* __restrict__ gsums, int N) {
    int tid = threadIdx.x;
    int c = tid & 63, q = tid >> 6;
    float sc, sh_;
    bn_coeff(bsp, gamp, betp, c, 1.f / (float)N, sc, sh_);
    int n0 = blockIdx.x * POOL_TILE;
    int nEnd = n0 + POOL_TILE; if (nEnd > N) nEnd = N;
    int g = -1;
    float acc = 0.f;
    for (int n = n0 + q; n < nEnd; n += 4) {
        int b = batch[n];
        if (b != g) {
            if (g >= 0) atomicAdd(&gsums[(size_t)g * 64 + c], acc);
            g = b; acc = 0.f;
        }
        acc += fmaxf(fmaf(h[(size_t)n * 64 + c], sc, sh_), 0.f);
    }
    if (g >= 0) atomicAdd(&gsums[(size_t)g * 64 + c], acc);
}

// ------- pool phase 2: divide by count + MLP head (one 64-thread block / graph) -
__global__ void k_head(const float* __restrict__ gsums, const int* __restrict__ batch,
                       const float* __restrict__ Wl1, const float* __restrict__ bl1,
                       const float* __restrict__ Wl2, const float* __restrict__ bl2,
                       float* __restrict__ out, int N) {
    int g = blockIdx.x;
    int c = threadIdx.x;  // 64 threads
    int lo = 0, hi = N;
    while (lo < hi) { int mid = (lo + hi) >> 1; if (batch[mid] < g) lo = mid + 1; else hi = mid; }
    int start = lo;
    hi = N;
    while (lo < hi) { int mid = (lo + hi) >> 1; if (batch[mid] < g + 1) lo = mid + 1; else hi = mid; }
    int cnt = lo - start;
    float denom = (float)(cnt > 0 ? cnt : 1);
    __shared__ float gS[64], yS[64];
    gS[c] = gsums[(size_t)g * 64 + c] / denom;
    __syncthreads();
    float y = bl1[c];
    for (int k = 0; k < 64; ++k) y += gS[k] * Wl1[k * 64 + c];
    yS[c] = fmaxf(y, 0.f);
    __syncthreads();
    if (c < 3) {
        float o = bl2[c];
        for (int k = 0; k < 64; ++k) o += yS[k] * Wl2[k * 3 + c];
        out[g * 3 + c] = o;
    }
}

extern "C" void kernel_launch(void* const* d_in, const int* in_sizes, int n_in,
                              void* d_out, int out_size, void* d_ws, size_t ws_size,
                              hipStream_t stream) {
    const float* x     = (const float*)d_in[0];
    const int*   eid   = (const int*)d_in[1];
    const float* attr  = (const float*)d_in[2];
    const int*   batch = (const int*)d_in[3];
    const float* Wemb  = (const float*)d_in[4];
    const float* bemb  = (const float*)d_in[5];
    const float* W1    = (const float*)d_in[6];
    const float* b1    = (const float*)d_in[7];
    const float* W2    = (const float*)d_in[8];
    const float* W3    = (const float*)d_in[9];
    const float* b3    = (const float*)d_in[10];
    const float* gamma = (const float*)d_in[11];
    const float* beta  = (const float*)d_in[12];
    const float* Wl1   = (const float*)d_in[13];
    const float* bl1   = (const float*)d_in[14];
    const float* Wl2   = (const float*)d_in[15];
    const float* bl2   = (const float*)d_in[16];

    int N = in_sizes[3];
    int E = in_sizes[2];
    int L = in_sizes[7] / 64;
    int G = out_size / 3;

    const int* src = eid;
    const int* dst = eid + E;

    float* ws      = (float*)d_ws;
    float* h       = ws;                       // N*64
    float* S       = h + (size_t)N * 64;       // N*64
    float* degw    = S + (size_t)N * 64;       // N
    float* g4      = degw + N;                 // N*4
    float* bnstats = g4 + (size_t)N * 4;       // 3*128 (per-layer slots)
    float* gsums   = bnstats + 3 * 128;        // G*64
    int*   deg     = (int*)(gsums + (size_t)G * 64);  // N
    int*   rowptr  = deg + N;                  // N+2
    int*   bsum    = rowptr + (N + 2);         // 1024
    int*   gcur    = bsum + 1024;              // 1024 (bucket cursors)
    unsigned long long* edata = (unsigned long long*)(gcur + 1024);  // E
    unsigned long long* tmp   = edata + E;                           // E

    int nScanBlocks = (N + 1023) / 1024;
    int NB = (N + 255) >> 8;  // 256-node buckets (requires N < 2^24, NB <= 1024)

    // ---- CSR build + two-level counting sort of edges by dst ----
    hipMemsetAsync(deg, 0, (size_t)N * sizeof(int), stream);
    hipMemsetAsync(bnstats, 0, 3 * 128 * sizeof(float), stream);
    k_hist<<<(E + 255) / 256, 256, 0, stream>>>(dst, deg, E);
    k_blocksum<<<nScanBlocks, 256, 0, stream>>>(deg, bsum, N);
    k_scanpartials<<<1, 1024, 0, stream>>>(bsum, nScanBlocks);
    k_applyscan<<<nScanBlocks, 256, 0, stream>>>(deg, bsum, rowptr, gcur, N, E);
    k_binA<<<(E + ABLK - 1) / ABLK, 1024, 0, stream>>>(src, dst, attr, gcur, tmp, E, N);
    k_binB<<<NB, 256, 0, stream>>>(rowptr, tmp, edata, N);

    // ---- layers: split kernels, lazy BN, per-layer stats slots ----
    int gGrid = (N * 64 + 255) / 256;
    for (int l = 0; l < L; ++l) {
        const float* bsp  = bnstats + (size_t)(l > 0 ? l - 1 : 0) * 128;
        const float* gamp = gamma + (size_t)(l > 0 ? l - 1 : 0) * 64;
        const float* betp = beta + (size_t)(l > 0 ? l - 1 : 0) * 64;
        if (l == 0) {
            // layer 0: 4-channel gather on raw x; S0/x0 reconstructed in update
            k_gather4<<<(N + 255) / 256, 256, 0, stream>>>(rowptr, edata, x, g4, degw, N);
            k_update<0, 1><<<512, 512, 0, stream>>>(S, h, degw, x, g4, Wemb, bemb,
                                                    bsp, gamp, betp,
                                                    W1, b1, W2, W3, b3, bnstats, N);
        } else {
            k_gather<1, 0><<<gGrid, 256, 0, stream>>>(rowptr, edata, h, bsp, gamp, betp,
                                                      S, degw, N);
            k_update<1, 0><<<512, 512, 0, stream>>>(S, h, degw, nullptr, nullptr,
                                                    nullptr, nullptr, bsp, gamp, betp,
                                                    W1 + (size_t)l * 4096, b1 + (size_t)l * 64,
                                                    W2 + (size_t)l * 4096, W3 + (size_t)l * 4096,
                                                    b3 + (size_t)l * 64,
                                                    bnstats + (size_t)l * 128, N);
        }
    }

    // ---- pool (applies final BN affine + relu lazily) + head ----
    hipMemsetAsync(gsums, 0, (size_t)G * 64 * sizeof(float), stream);
    k_poolsum<<<(N + POOL_TILE - 1) / POOL_TILE, 256, 0, stream>>>(
        h, batch, bnstats + (size_t)(L - 1) * 128, gamma + (size_t)(L - 1) * 64,
        beta + (size_t)(L - 1) * 64, gsums, N);
    k_head<<<G, 64, 0, stream>>>(gsums, batch, Wl1, bl1, Wl2, bl2, (float*)d_out, N);
}